// Round 2
// baseline (1863.627 us; speedup 1.0000x reference)
//
#include <hip/hip_runtime.h>

#define B_ 8
#define N_ 8192
#define DIN_ 16
#define G_ 512
#define K_ 32
#define OD_ 256
#define PD_ 128
#define MD_ 128
#define CE_ 259

// ---------------- prep: transpose weights for coalesced reads ----------------
__global__ void prep_kernel(const float* __restrict__ w_lin1,
                            const float* __restrict__ down_w,
                            const float* __restrict__ up_w,
                            float* __restrict__ wt,
                            float* __restrict__ dwt,
                            float* __restrict__ uwt) {
    int i = blockIdx.x * blockDim.x + threadIdx.x;
    if (i < OD_ * CE_) {                       // wt[j][c] = w_lin1[c][j]
        int c = i / CE_, j = i % CE_;
        wt[j * OD_ + c] = w_lin1[i];
    }
    if (i < 2 * MD_ * OD_) {                   // dwt[l][c][m] = down_w[l][m][c]
        int l = i / (MD_ * OD_); int r = i % (MD_ * OD_);
        int m = r / OD_, c = r % OD_;
        dwt[l * (OD_ * MD_) + c * MD_ + m] = down_w[i];
    }
    if (i < 2 * OD_ * MD_) {                   // uwt[l][m][c] = up_w[l][c][m]
        int l = i / (OD_ * MD_); int r = i % (OD_ * MD_);
        int c = r / MD_, m = r % MD_;
        uwt[l * (MD_ * OD_) + m * OD_ + c] = up_w[i];
    }
}

// ---------------- block argmax/argmin on packed (value,idx) u64 keys ----------------
__device__ __forceinline__ int block_argmax_u(unsigned long long key,
                                              unsigned long long* wred, int* sint, int nw) {
#pragma unroll
    for (int off = 32; off > 0; off >>= 1) {
        unsigned long long o = __shfl_xor(key, off);
        if (o > key) key = o;
    }
    int lane = threadIdx.x & 63, w = threadIdx.x >> 6;
    if (lane == 0) wred[w] = key;
    __syncthreads();
    if (threadIdx.x == 0) {
        unsigned long long best = wred[0];
        for (int i = 1; i < nw; ++i) if (wred[i] > best) best = wred[i];
        *sint = (int)(0xFFFFFFFFu - (unsigned)(best & 0xFFFFFFFFull));
    }
    __syncthreads();
    return *sint;
}

__device__ __forceinline__ int block_argmin_u(unsigned long long key,
                                              unsigned long long* wred, int* sint, int nw) {
#pragma unroll
    for (int off = 32; off > 0; off >>= 1) {
        unsigned long long o = __shfl_xor(key, off);
        if (o < key) key = o;
    }
    int lane = threadIdx.x & 63, w = threadIdx.x >> 6;
    if (lane == 0) wred[w] = key;
    __syncthreads();
    if (threadIdx.x == 0) {
        unsigned long long best = wred[0];
        for (int i = 1; i < nw; ++i) if (wred[i] < best) best = wred[i];
        *sint = (int)(best & 0xFFFFFFFFull);
    }
    __syncthreads();
    return *sint;
}

// ---------------- FPS: 512 sequential argmax steps, one block per batch ----------------
// Points live in registers (8/thread); winner broadcasts coords via 3 shared floats.
__global__ __launch_bounds__(1024)
void fps_kernel(const float* __restrict__ xyz, int* __restrict__ sel) {
#pragma clang fp contract(off)
    __shared__ unsigned long long wred[16];
    __shared__ int sint;
    __shared__ float cpt[3];
    int b = blockIdx.x, tid = threadIdx.x;
    const float* xb = xyz + (size_t)b * N_ * 3;
    float px[8], py[8], pz[8], mind[8];
    int base = tid * 8;
    float bv = -1.f; int bi = base;
#pragma unroll
    for (int j = 0; j < 8; ++j) {
        px[j] = xb[(base + j) * 3];
        py[j] = xb[(base + j) * 3 + 1];
        pz[j] = xb[(base + j) * 3 + 2];
        mind[j] = 1e10f;
        float ssum = (px[j] * px[j] + py[j] * py[j]) + pz[j] * pz[j];
        if (ssum > bv) { bv = ssum; bi = base + j; }
    }
    unsigned long long key = ((unsigned long long)__float_as_uint(bv) << 32)
                           | (unsigned long long)(0xFFFFFFFFu - (unsigned)bi);
    int cur = block_argmax_u(key, wred, &sint, 16);
    for (int it = 0; it < G_; ++it) {
        if (tid == 0) sel[b * G_ + it] = cur;
        if ((cur >> 3) == tid) {
            int j = cur & 7;
            cpt[0] = px[j]; cpt[1] = py[j]; cpt[2] = pz[j];
        }
        __syncthreads();
        float cx = cpt[0], cy = cpt[1], cz = cpt[2];
        bv = -1.f; bi = base;
#pragma unroll
        for (int j = 0; j < 8; ++j) {
            float dx = px[j] - cx, dy = py[j] - cy, dz = pz[j] - cz;
            float d = (dx * dx + dy * dy) + dz * dz;
            mind[j] = fminf(mind[j], d);
            if (mind[j] > bv) { bv = mind[j]; bi = base + j; }
        }
        key = ((unsigned long long)__float_as_uint(bv) << 32)
            | (unsigned long long)(0xFFFFFFFFu - (unsigned)bi);
        cur = block_argmax_u(key, wred, &sint, 16);
    }
}

// ---------------- KNN: per query, 32 iterative argmins over 8192 dists ----------------
__global__ __launch_bounds__(256)
void knn_kernel(const float* __restrict__ xyz, const int* __restrict__ sel,
                int* __restrict__ nn) {
#pragma clang fp contract(off)
    __shared__ float dld[N_];
    __shared__ unsigned long long wred[4];
    __shared__ int sint;
    int gb = blockIdx.x; int b = gb >> 9, s = gb & (G_ - 1);
    const float* xb = xyz + (size_t)b * N_ * 3;
    int q = sel[b * G_ + s];
    float qx = xb[q * 3], qy = xb[q * 3 + 1], qz = xb[q * 3 + 2];
    float qq = (qx * qx + qy * qy) + qz * qz;
    int tid = threadIdx.x;
    int base = tid * 32;
    const float FINF = __builtin_inff();
    float lv = FINF; int li = base;
    for (int j = 0; j < 32; ++j) {
        int n = base + j;
        float rx = xb[n * 3], ry = xb[n * 3 + 1], rz = xb[n * 3 + 2];
        float rr = (rx * rx + ry * ry) + rz * rz;
        float dt = (qx * rx + qy * ry) + qz * rz;
        float d = (qq + rr) - 2.0f * dt;
        d = fmaxf(d, 0.f);
        dld[n] = d;
        if (d < lv) { lv = d; li = n; }
    }
    __syncthreads();
    for (int t = 0; t < K_; ++t) {
        unsigned long long key = ((unsigned long long)__float_as_uint(lv) << 32)
                               | (unsigned long long)(unsigned)li;
        int win = block_argmin_u(key, wred, &sint, 4);
        if (tid == 0) nn[(size_t)gb * K_ + t] = win;
        if ((win >> 5) == tid) {
            dld[win] = FINF;
            lv = FINF; li = base;
            for (int j = 0; j < 32; ++j) {
                float d = dld[base + j];
                if (d < lv) { lv = d; li = base + j; }
            }
        }
        __syncthreads();
    }
}

// ---------------- global std (ddof=1) of rel_raw, f64 accumulation ----------------
__global__ void std_acc_kernel(const float* __restrict__ xyz, const int* __restrict__ sel,
                               const int* __restrict__ nn, double* __restrict__ acc) {
    int tot = B_ * G_ * K_;
    int stride = gridDim.x * blockDim.x;
    double ls = 0.0, lss = 0.0;
    for (int idx = blockIdx.x * blockDim.x + threadIdx.x; idx < tot; idx += stride) {
        int b = idx >> 14; int g = (idx >> 5) & (G_ - 1);
        int n = nn[idx]; int a = sel[b * G_ + g];
        const float* xb = xyz + (size_t)b * N_ * 3;
#pragma unroll
        for (int c = 0; c < 3; ++c) {
            float v = xb[n * 3 + c] - xb[a * 3 + c];
            ls += (double)v; lss += (double)v * (double)v;
        }
    }
#pragma unroll
    for (int off = 32; off > 0; off >>= 1) {
        ls += __shfl_down(ls, off); lss += __shfl_down(lss, off);
    }
    if ((threadIdx.x & 63) == 0) { atomicAdd(acc, ls); atomicAdd(acc + 1, lss); }
}

__global__ void std_fin_kernel(const double* __restrict__ acc, float* __restrict__ stdp) {
    double s = acc[0], ss = acc[1];
    double M = (double)(B_ * G_ * K_ * 3);
    double var = (ss - s * s / M) / (M - 1.0);
    stdp[0] = (float)sqrt(var) + 1e-5f;
}

// ---------------- fused per-group pipeline: embed + lin1 + 2 residual blocks + reduce ----------------
__global__ __launch_bounds__(256, 2)
void group_kernel(const float* __restrict__ xyz, const float* __restrict__ feat,
                  const float* __restrict__ wEg, const float* __restrict__ bE,
                  const float* __restrict__ gE, const float* __restrict__ beE,
                  const int* __restrict__ sel, const int* __restrict__ nn,
                  const float* __restrict__ wt, const float* __restrict__ dwt,
                  const float* __restrict__ uwt,
                  const float* __restrict__ g_lin1, const float* __restrict__ be_lin1,
                  const float* __restrict__ down_b, const float* __restrict__ gd,
                  const float* __restrict__ bd,
                  const float* __restrict__ up_b, const float* __restrict__ gu,
                  const float* __restrict__ bu,
                  const float* __restrict__ stdp, float* __restrict__ out) {
    __shared__ float xls[OD_][36];      // x tile [c][k]; first 2720 floats double as embed scratch
    __shared__ float ebuf[K_ * 260];    // E (32x260) until lin1 done; then hls (128x36)
    __shared__ float wk[K_];
    __shared__ int nns[K_];
    __shared__ float anch[3];
    float (*E)[260]  = (float(*)[260])ebuf;
    float (*hls)[36] = (float(*)[36])ebuf;
    float* wEt = &xls[0][0];            // 16x128 transposed embed weights
    float* fL  = wEt + 2048;            // 33x16 gathered feats
    float* lcf = fL + 544;              // 128 anchor embed

    int gb = blockIdx.x; int b = gb >> 9, g = gb & (G_ - 1);
    int tid = threadIdx.x;
    const float* xb = xyz + (size_t)b * N_ * 3;
    int a = sel[b * G_ + g];
    if (tid < K_) nns[tid] = nn[(size_t)gb * K_ + tid];
    if (tid < 3)  anch[tid] = xb[a * 3 + tid];
    __syncthreads();

    // ---- stage embed weights (transposed: conflict-free) + feats
    for (int idx = tid; idx < DIN_ * PD_; idx += 256) {
        int i = idx >> 7, c = idx & 127;
        wEt[idx] = wEg[c * DIN_ + i];   // wEt[i][c] = w_embed[c][i]
    }
    const float* fb = feat + (size_t)b * N_ * DIN_;
    for (int idx = tid; idx < 33 * DIN_; idx += 256) {
        int k = idx >> 4, j = idx & 15;
        int n = (k < K_) ? nns[k] : a;
        fL[idx] = fb[(size_t)n * DIN_ + j];
    }
    __syncthreads();

    const float s_bn = 1.0f / sqrtf(1.0f + 1e-5f);
    // ---- on-the-fly embed: E[k][0:128] and lcf (anchor)
    for (int idx = tid; idx < 33 * PD_; idx += 256) {
        int k = idx >> 7, c = idx & 127;
        const float* f = &fL[k * DIN_];
        float acc2 = 0.f;
#pragma unroll
        for (int i = 0; i < DIN_; ++i) acc2 += wEt[i * PD_ + c] * f[i];
        acc2 = (acc2 + bE[c]) * s_bn * gE[c] + beE[c];
        acc2 = fmaxf(acc2, 0.f);
        if (k < K_) E[k][c] = acc2; else lcf[c] = acc2;
    }
    // E[k][128:131] = raw knn xyz
    for (int idx = tid; idx < K_ * 3; idx += 256) {
        int k = idx / 3, c = idx - k * 3;
        E[k][PD_ + c] = xb[nns[k] * 3 + c];
    }
    if (tid < K_) {
#pragma clang fp contract(off)
        float sd = stdp[0];
        int n = nns[tid];
        float rx = (xb[n * 3]     - anch[0]) / sd - anch[0];
        float ry = (xb[n * 3 + 1] - anch[1]) / sd - anch[1];
        float rz = (xb[n * 3 + 2] - anch[2]) / sd - anch[2];
        float nrm = sqrtf((rx * rx + ry * ry) + rz * rz);
        wk[tid] = expf(-0.5f * nrm);
    }
    __syncthreads();
    // E[k][131:259] = anchor embed broadcast
    for (int idx = tid; idx < K_ * PD_; idx += 256) {
        int k = idx >> 7, j = idx & 127;
        E[k][131 + j] = lcf[j];
    }
    __syncthreads();

    // ---- lin1 GEMM: thread owns 4 channels x 8 k
    int c0 = (tid & 63) * 4, k0 = (tid >> 6) * 8;
    float acc[4][8];
#pragma unroll
    for (int cc = 0; cc < 4; ++cc)
#pragma unroll
        for (int kk = 0; kk < 8; ++kk) acc[cc][kk] = 0.f;

    for (int j0 = 0; j0 < 256; j0 += 4) {
        float4 w0 = *(const float4*)&wt[(j0 + 0) * OD_ + c0];
        float4 w1 = *(const float4*)&wt[(j0 + 1) * OD_ + c0];
        float4 w2 = *(const float4*)&wt[(j0 + 2) * OD_ + c0];
        float4 w3 = *(const float4*)&wt[(j0 + 3) * OD_ + c0];
#pragma unroll
        for (int kk = 0; kk < 8; ++kk) {
            float4 e = *(const float4*)&E[k0 + kk][j0];
            acc[0][kk] += w0.x * e.x + w1.x * e.y + w2.x * e.z + w3.x * e.w;
            acc[1][kk] += w0.y * e.x + w1.y * e.y + w2.y * e.z + w3.y * e.w;
            acc[2][kk] += w0.z * e.x + w1.z * e.y + w2.z * e.z + w3.z * e.w;
            acc[3][kk] += w0.w * e.x + w1.w * e.y + w2.w * e.z + w3.w * e.w;
        }
    }
    for (int j = 256; j < CE_; ++j) {   // tail (259 = 256 + 3)
        float wv0 = wt[j * OD_ + c0], wv1 = wt[j * OD_ + c0 + 1];
        float wv2 = wt[j * OD_ + c0 + 2], wv3 = wt[j * OD_ + c0 + 3];
#pragma unroll
        for (int kk = 0; kk < 8; ++kk) {
            float e = E[k0 + kk][j];
            acc[0][kk] += wv0 * e; acc[1][kk] += wv1 * e;
            acc[2][kk] += wv2 * e; acc[3][kk] += wv3 * e;
        }
    }
    __syncthreads();   // all E reads done before ebuf is reused (hls) and xls overwritten
#pragma unroll
    for (int cc = 0; cc < 4; ++cc) {
        float gg = g_lin1[c0 + cc], bb = be_lin1[c0 + cc];
#pragma unroll
        for (int kk = 0; kk < 8; ++kk) {
            float v = acc[cc][kk] * s_bn * gg + bb;
            v = fmaxf(v, 0.f);
            v *= wk[k0 + kk];
            xls[c0 + cc][k0 + kk] = v;
        }
    }
    __syncthreads();

    // ---- residual blocks
    for (int l = 0; l < 2; ++l) {
        // down: h[m][k] = relu(bn(dw @ x + db)), thread owns 4 m x 4 k
        int m0 = (tid & 31) * 4, kq0 = (tid >> 5) * 4;
        float hacc[4][4];
#pragma unroll
        for (int mm = 0; mm < 4; ++mm)
#pragma unroll
            for (int kk = 0; kk < 4; ++kk) hacc[mm][kk] = 0.f;
        const float* dw = dwt + l * (OD_ * MD_);
        for (int j = 0; j < OD_; ++j) {
            float4 wv = *(const float4*)&dw[j * MD_ + m0];
            float4 xv = *(const float4*)&xls[j][kq0];
            hacc[0][0] += wv.x * xv.x; hacc[0][1] += wv.x * xv.y; hacc[0][2] += wv.x * xv.z; hacc[0][3] += wv.x * xv.w;
            hacc[1][0] += wv.y * xv.x; hacc[1][1] += wv.y * xv.y; hacc[1][2] += wv.y * xv.z; hacc[1][3] += wv.y * xv.w;
            hacc[2][0] += wv.z * xv.x; hacc[2][1] += wv.z * xv.y; hacc[2][2] += wv.z * xv.z; hacc[2][3] += wv.z * xv.w;
            hacc[3][0] += wv.w * xv.x; hacc[3][1] += wv.w * xv.y; hacc[3][2] += wv.w * xv.z; hacc[3][3] += wv.w * xv.w;
        }
#pragma unroll
        for (int mm = 0; mm < 4; ++mm) {
            float db = down_b[l * MD_ + m0 + mm];
            float gv = gd[l * MD_ + m0 + mm], bv2 = bd[l * MD_ + m0 + mm];
#pragma unroll
            for (int kk = 0; kk < 4; ++kk) {
                float v = (hacc[mm][kk] + db) * s_bn * gv + bv2;
                hls[m0 + mm][kq0 + kk] = fmaxf(v, 0.f);
            }
        }
        __syncthreads();
        // up: o[c][k] = bn(uw @ h + ub); x = relu(o + x); thread owns 4 c x 8 k
        float uacc[4][8];
#pragma unroll
        for (int cc = 0; cc < 4; ++cc)
#pragma unroll
            for (int kk = 0; kk < 8; ++kk) uacc[cc][kk] = 0.f;
        const float* uw = uwt + l * (MD_ * OD_);
        for (int j = 0; j < MD_; ++j) {
            float4 wv = *(const float4*)&uw[j * OD_ + c0];
            float4 h0 = *(const float4*)&hls[j][k0];
            float4 h1 = *(const float4*)&hls[j][k0 + 4];
            uacc[0][0] += wv.x * h0.x; uacc[0][1] += wv.x * h0.y; uacc[0][2] += wv.x * h0.z; uacc[0][3] += wv.x * h0.w;
            uacc[0][4] += wv.x * h1.x; uacc[0][5] += wv.x * h1.y; uacc[0][6] += wv.x * h1.z; uacc[0][7] += wv.x * h1.w;
            uacc[1][0] += wv.y * h0.x; uacc[1][1] += wv.y * h0.y; uacc[1][2] += wv.y * h0.z; uacc[1][3] += wv.y * h0.w;
            uacc[1][4] += wv.y * h1.x; uacc[1][5] += wv.y * h1.y; uacc[1][6] += wv.y * h1.z; uacc[1][7] += wv.y * h1.w;
            uacc[2][0] += wv.z * h0.x; uacc[2][1] += wv.z * h0.y; uacc[2][2] += wv.z * h0.z; uacc[2][3] += wv.z * h0.w;
            uacc[2][4] += wv.z * h1.x; uacc[2][5] += wv.z * h1.y; uacc[2][6] += wv.z * h1.z; uacc[2][7] += wv.z * h1.w;
            uacc[3][0] += wv.w * h0.x; uacc[3][1] += wv.w * h0.y; uacc[3][2] += wv.w * h0.z; uacc[3][3] += wv.w * h0.w;
            uacc[3][4] += wv.w * h1.x; uacc[3][5] += wv.w * h1.y; uacc[3][6] += wv.w * h1.z; uacc[3][7] += wv.w * h1.w;
        }
        float nx[4][8];
#pragma unroll
        for (int cc = 0; cc < 4; ++cc) {
            float ub = up_b[l * OD_ + c0 + cc];
            float gv = gu[l * OD_ + c0 + cc], bv2 = bu[l * OD_ + c0 + cc];
#pragma unroll
            for (int kk = 0; kk < 8; ++kk) {
                float v = (uacc[cc][kk] + ub) * s_bn * gv + bv2;
                v += xls[c0 + cc][k0 + kk];
                nx[cc][kk] = fmaxf(v, 0.f);
            }
        }
        __syncthreads();
#pragma unroll
        for (int cc = 0; cc < 4; ++cc) {
            *(float4*)&xls[c0 + cc][k0]     = make_float4(nx[cc][0], nx[cc][1], nx[cc][2], nx[cc][3]);
            *(float4*)&xls[c0 + cc][k0 + 4] = make_float4(nx[cc][4], nx[cc][5], nx[cc][6], nx[cc][7]);
        }
        __syncthreads();
    }

    // ---- final: max_k + mean_k
    float mx = -__builtin_inff(), sm = 0.f;
#pragma unroll
    for (int k = 0; k < K_; ++k) {
        float v = xls[tid][k];
        mx = fmaxf(mx, v);
        sm += v;
    }
    out[((size_t)b * OD_ + tid) * G_ + g] = mx + sm * (1.0f / 32.0f);
}

extern "C" void kernel_launch(void* const* d_in, const int* in_sizes, int n_in,
                              void* d_out, int out_size, void* d_ws, size_t ws_size,
                              hipStream_t stream) {
    const float* xyz     = (const float*)d_in[0];
    const float* feat    = (const float*)d_in[1];
    const float* w_embed = (const float*)d_in[2];
    const float* b_embed = (const float*)d_in[3];
    const float* g_embed = (const float*)d_in[4];
    const float* be_embed= (const float*)d_in[5];
    const float* w_lin1  = (const float*)d_in[6];
    const float* g_lin1  = (const float*)d_in[7];
    const float* be_lin1 = (const float*)d_in[8];
    const float* down_w  = (const float*)d_in[9];
    const float* down_b  = (const float*)d_in[10];
    const float* gd      = (const float*)d_in[11];
    const float* bd      = (const float*)d_in[12];
    const float* up_w    = (const float*)d_in[13];
    const float* up_b    = (const float*)d_in[14];
    const float* gu      = (const float*)d_in[15];
    const float* bu      = (const float*)d_in[16];
    float* out = (float*)d_out;

    // workspace layout (~1.33 MB total)
    float* wt  = (float*)d_ws;                        // 259*256
    float* dwt = wt + OD_ * CE_;                      // 2*256*128
    float* uwt = dwt + 2 * OD_ * MD_;                 // 2*128*256
    int* sel   = (int*)(uwt + 2 * OD_ * MD_);         // 8*512
    int* nn    = sel + B_ * G_;                       // 8*512*32
    double* acc = (double*)(nn + B_ * G_ * K_);       // 2 doubles (8B aligned)
    float* stdp = (float*)(acc + 2);

    hipMemsetAsync(acc, 0, 2 * sizeof(double), stream);
    prep_kernel<<<(OD_ * CE_ + 255) / 256, 256, 0, stream>>>(w_lin1, down_w, up_w, wt, dwt, uwt);
    fps_kernel<<<B_, 1024, 0, stream>>>(xyz, sel);
    knn_kernel<<<B_ * G_, 256, 0, stream>>>(xyz, sel, nn);
    std_acc_kernel<<<256, 256, 0, stream>>>(xyz, sel, nn, acc);
    std_fin_kernel<<<1, 1, 0, stream>>>(acc, stdp);
    group_kernel<<<B_ * G_, 256, 0, stream>>>(xyz, feat, w_embed, b_embed, g_embed, be_embed,
        sel, nn, wt, dwt, uwt, g_lin1, be_lin1, down_b, gd, bd, up_b, gu, bu, stdp, out);
}

// Round 4
// 1596.559 us; speedup vs baseline: 1.1673x; 1.1673x over previous
//
#include <hip/hip_runtime.h>

#define B_ 8
#define N_ 8192
#define DIN_ 16
#define G_ 512
#define K_ 32
#define OD_ 256
#define PD_ 128
#define MD_ 128
#define CE_ 259
#define XST 34   // xls/hls row stride (floats): float2-aligned, low-conflict

// ---------------- prep: transpose weights for coalesced reads ----------------
__global__ void prep_kernel(const float* __restrict__ w_lin1,
                            const float* __restrict__ down_w,
                            const float* __restrict__ up_w,
                            float* __restrict__ wt,
                            float* __restrict__ dwt,
                            float* __restrict__ uwt) {
    int i = blockIdx.x * blockDim.x + threadIdx.x;
    if (i < OD_ * CE_) {                       // wt[j][c] = w_lin1[c][j]
        int c = i / CE_, j = i % CE_;
        wt[j * OD_ + c] = w_lin1[i];
    }
    if (i < 2 * MD_ * OD_) {                   // dwt[l][c][m] = down_w[l][m][c]
        int l = i / (MD_ * OD_); int r = i % (MD_ * OD_);
        int m = r / OD_, c = r % OD_;
        dwt[l * (OD_ * MD_) + c * MD_ + m] = down_w[i];
    }
    if (i < 2 * OD_ * MD_) {                   // uwt[l][m][c] = up_w[l][c][m]
        int l = i / (OD_ * MD_); int r = i % (OD_ * MD_);
        int c = r / MD_, m = r % MD_;
        uwt[l * (MD_ * OD_) + m * OD_ + c] = up_w[i];
    }
}

// ---------------- FPS: 512 sequential argmax steps, one barrier per step ----------------
__global__ __launch_bounds__(1024)
void fps_kernel(const float* __restrict__ xyz, int* __restrict__ sel) {
#pragma clang fp contract(off)
    __shared__ float sx[N_], sy[N_], sz[N_];
    __shared__ unsigned long long wred[2][16];
    int b = blockIdx.x, tid = threadIdx.x;
    const float* xb = xyz + (size_t)b * N_ * 3;
    for (int i = tid; i < N_; i += 1024) {
        sx[i] = xb[i * 3]; sy[i] = xb[i * 3 + 1]; sz[i] = xb[i * 3 + 2];
    }
    __syncthreads();
    float px[8], py[8], pz[8], mind[8];
    float bv = -1.f; int bi = 0;
#pragma unroll
    for (int j = 0; j < 8; ++j) {
        int idx = tid + j * 1024;
        px[j] = sx[idx]; py[j] = sy[idx]; pz[j] = sz[idx];
        mind[j] = 1e10f;
        float ss = (px[j] * px[j] + py[j] * py[j]) + pz[j] * pz[j];
        if (ss > bv) { bv = ss; bi = idx; }
    }
    unsigned long long key = ((unsigned long long)__float_as_uint(bv) << 32)
                           | (unsigned long long)(0xFFFFFFFFu - (unsigned)bi);
#pragma unroll
    for (int off = 32; off > 0; off >>= 1) {
        unsigned long long o = __shfl_xor(key, off); if (o > key) key = o;
    }
    if ((tid & 63) == 0) wred[0][tid >> 6] = key;
    __syncthreads();
    unsigned long long best = wred[0][0];
#pragma unroll
    for (int i = 1; i < 16; ++i) { unsigned long long v = wred[0][i]; if (v > best) best = v; }
    int cur = (int)(0xFFFFFFFFu - (unsigned)(best & 0xFFFFFFFFull));

    for (int it = 0; it < G_; ++it) {
        if (tid == 0) sel[b * G_ + it] = cur;
        float cx = sx[cur], cy = sy[cur], cz = sz[cur];
        bv = -1.f; bi = 0;
#pragma unroll
        for (int j = 0; j < 8; ++j) {
            float dx = px[j] - cx, dy = py[j] - cy, dz = pz[j] - cz;
            float d = (dx * dx + dy * dy) + dz * dz;
            float m = fminf(mind[j], d); mind[j] = m;
            if (m > bv) { bv = m; bi = tid + j * 1024; }
        }
        key = ((unsigned long long)__float_as_uint(bv) << 32)
            | (unsigned long long)(0xFFFFFFFFu - (unsigned)bi);
#pragma unroll
        for (int off = 32; off > 0; off >>= 1) {
            unsigned long long o = __shfl_xor(key, off); if (o > key) key = o;
        }
        int pb = (it + 1) & 1;
        if ((tid & 63) == 0) wred[pb][tid >> 6] = key;
        __syncthreads();
        best = wred[pb][0];
#pragma unroll
        for (int i = 1; i < 16; ++i) { unsigned long long v = wred[pb][i]; if (v > best) best = v; }
        cur = (int)(0xFFFFFFFFu - (unsigned)(best & 0xFFFFFFFFull));
    }
}

// ---------------- KNN: strided ownership (conflict-free), one barrier per pick ----------------
__global__ __launch_bounds__(256)
void knn_kernel(const float* __restrict__ xyz, const int* __restrict__ sel,
                int* __restrict__ nn) {
#pragma clang fp contract(off)
    __shared__ float dld[N_];
    __shared__ unsigned long long wred[2][4];
    int gb = blockIdx.x; int b = gb >> 9, s = gb & (G_ - 1);
    const float* xb = xyz + (size_t)b * N_ * 3;
    int q = sel[b * G_ + s];
    float qx = xb[q * 3], qy = xb[q * 3 + 1], qz = xb[q * 3 + 2];
    float qq = (qx * qx + qy * qy) + qz * qz;
    int tid = threadIdx.x;
    const float FINF = __builtin_inff();
    float lv = FINF; int li = tid;
    for (int j = 0; j < 32; ++j) {
        int n = tid + j * 256;
        float rx = xb[n * 3], ry = xb[n * 3 + 1], rz = xb[n * 3 + 2];
        float rr = (rx * rx + ry * ry) + rz * rz;
        float dt = (qx * rx + qy * ry) + qz * rz;
        float d = (qq + rr) - 2.0f * dt;
        d = fmaxf(d, 0.f);
        dld[n] = d;
        if (d < lv) { lv = d; li = n; }
    }
    unsigned long long key = ((unsigned long long)__float_as_uint(lv) << 32) | (unsigned)li;
#pragma unroll
    for (int off = 32; off > 0; off >>= 1) {
        unsigned long long o = __shfl_xor(key, off); if (o < key) key = o;
    }
    if ((tid & 63) == 0) wred[0][tid >> 6] = key;
    __syncthreads();
    unsigned long long best = wred[0][0];
#pragma unroll
    for (int i = 1; i < 4; ++i) { unsigned long long v = wred[0][i]; if (v < best) best = v; }
    int win = (int)(best & 0xFFFFFFFFull);

    for (int t = 0; t < K_; ++t) {
        if (tid == 0) nn[(size_t)gb * K_ + t] = win;
        if ((win & 255) == tid) {
            dld[win] = FINF;
            lv = FINF; li = tid;
            for (int j = 0; j < 32; ++j) {
                float d = dld[tid + j * 256];
                if (d < lv) { lv = d; li = tid + j * 256; }
            }
        }
        key = ((unsigned long long)__float_as_uint(lv) << 32) | (unsigned)li;
#pragma unroll
        for (int off = 32; off > 0; off >>= 1) {
            unsigned long long o = __shfl_xor(key, off); if (o < key) key = o;
        }
        int pb = (t + 1) & 1;
        if ((tid & 63) == 0) wred[pb][tid >> 6] = key;
        __syncthreads();
        best = wred[pb][0];
#pragma unroll
        for (int i = 1; i < 4; ++i) { unsigned long long v = wred[pb][i]; if (v < best) best = v; }
        win = (int)(best & 0xFFFFFFFFull);
    }
}

// ---------------- global std (ddof=1) of rel_raw, f64 accumulation ----------------
__global__ void std_acc_kernel(const float* __restrict__ xyz, const int* __restrict__ sel,
                               const int* __restrict__ nn, double* __restrict__ acc) {
    int tot = B_ * G_ * K_;
    int stride = gridDim.x * blockDim.x;
    double ls = 0.0, lss = 0.0;
    for (int idx = blockIdx.x * blockDim.x + threadIdx.x; idx < tot; idx += stride) {
        int b = idx >> 14; int g = (idx >> 5) & (G_ - 1);
        int n = nn[idx]; int a = sel[b * G_ + g];
        const float* xb = xyz + (size_t)b * N_ * 3;
#pragma unroll
        for (int c = 0; c < 3; ++c) {
            float v = xb[n * 3 + c] - xb[a * 3 + c];
            ls += (double)v; lss += (double)v * (double)v;
        }
    }
#pragma unroll
    for (int off = 32; off > 0; off >>= 1) {
        ls += __shfl_down(ls, off); lss += __shfl_down(lss, off);
    }
    if ((threadIdx.x & 63) == 0) { atomicAdd(acc, ls); atomicAdd(acc + 1, lss); }
}

__global__ void std_fin_kernel(const double* __restrict__ acc, float* __restrict__ stdp) {
    double s = acc[0], ss = acc[1];
    double M = (double)(B_ * G_ * K_ * 3);
    double var = (ss - s * s / M) / (M - 1.0);
    stdp[0] = (float)sqrt(var) + 1e-5f;
}

// ---------------- fused per-group pipeline: embed + lin1 + 2 residual blocks + reduce ----------------
// LDS: xls 34816 + ebuf 17408 + ~700 = ~52.5 KB -> 3 blocks/CU
__global__ __launch_bounds__(256, 3)
void group_kernel(const float* __restrict__ xyz, const float* __restrict__ feat,
                  const float* __restrict__ wEg, const float* __restrict__ bE,
                  const float* __restrict__ gE, const float* __restrict__ beE,
                  const int* __restrict__ sel, const int* __restrict__ nn,
                  const float* __restrict__ wt, const float* __restrict__ dwt,
                  const float* __restrict__ uwt,
                  const float* __restrict__ g_lin1, const float* __restrict__ be_lin1,
                  const float* __restrict__ down_b, const float* __restrict__ gd,
                  const float* __restrict__ bd,
                  const float* __restrict__ up_b, const float* __restrict__ gu,
                  const float* __restrict__ bu,
                  const float* __restrict__ stdp, float* __restrict__ out) {
    __shared__ float xls[OD_][XST];     // x tile [c][k]; head doubles as embed scratch
    __shared__ float ebuf[4352];        // E (32x132) during lin1; hls (128x34) after
    __shared__ float wk[K_];
    __shared__ int nns[K_];
    __shared__ float anch[3];
    float (*E)[132]   = (float(*)[132])ebuf;
    float (*hls)[XST] = (float(*)[XST])ebuf;
    float* wEt = &xls[0][0];            // 16x128 transposed embed weights (2048 f)
    float* fL  = wEt + 2048;            // 33x16 gathered feats (544 f)
    float* lcf = fL + 544;              // 128 anchor embed

    int gb = blockIdx.x; int b = gb >> 9, g = gb & (G_ - 1);
    int tid = threadIdx.x;
    const float* xb = xyz + (size_t)b * N_ * 3;
    int a = sel[b * G_ + g];
    if (tid < K_) nns[tid] = nn[(size_t)gb * K_ + tid];
    if (tid < 3)  anch[tid] = xb[a * 3 + tid];
    __syncthreads();

    // ---- stage embed weights (transposed) + gathered feats
    for (int idx = tid; idx < DIN_ * PD_; idx += 256) {
        int i = idx >> 7, c = idx & 127;
        wEt[idx] = wEg[c * DIN_ + i];   // wEt[i][c] = w_embed[c][i]
    }
    const float* fb = feat + (size_t)b * N_ * DIN_;
    for (int idx = tid; idx < 33 * DIN_; idx += 256) {
        int k = idx >> 4, j = idx & 15;
        int n = (k < K_) ? nns[k] : a;
        fL[idx] = fb[(size_t)n * DIN_ + j];
    }
    __syncthreads();

    const float s_bn = 1.0f / sqrtf(1.0f + 1e-5f);
    // ---- on-the-fly embed: E[k][0:128] and lcf (anchor)
    for (int idx = tid; idx < 33 * PD_; idx += 256) {
        int k = idx >> 7, c = idx & 127;
        const float* f = &fL[k * DIN_];
        float acc2 = 0.f;
#pragma unroll
        for (int i = 0; i < DIN_; ++i) acc2 += wEt[i * PD_ + c] * f[i];
        acc2 = (acc2 + bE[c]) * s_bn * gE[c] + beE[c];
        acc2 = fmaxf(acc2, 0.f);
        if (k < K_) E[k][c] = acc2; else lcf[c] = acc2;
    }
    // E[k][128:131] = raw knn xyz
    for (int idx = tid; idx < K_ * 3; idx += 256) {
        int k = idx / 3, c = idx - k * 3;
        E[k][PD_ + c] = xb[nns[k] * 3 + c];
    }
    if (tid < K_) {
#pragma clang fp contract(off)
        float sd = stdp[0];
        int n = nns[tid];
        float rx = (xb[n * 3]     - anch[0]) / sd - anch[0];
        float ry = (xb[n * 3 + 1] - anch[1]) / sd - anch[1];
        float rz = (xb[n * 3 + 2] - anch[2]) / sd - anch[2];
        float nrm = sqrtf((rx * rx + ry * ry) + rz * rz);
        wk[tid] = expf(-0.5f * nrm);
    }
    __syncthreads();

    // ---- lin1: acc[c][k] = lcv[c] + sum_{j<131} wt[j][c]*E[k][j]
    int c0 = (tid & 63) * 4, k0 = (tid >> 6) * 8;
    // k-independent anchor term (cols 131..258 of expanded)
    float lcv0 = 0.f, lcv1 = 0.f, lcv2 = 0.f, lcv3 = 0.f;
    for (int j = 0; j < PD_; ++j) {
        float4 wv = *(const float4*)&wt[(131 + j) * OD_ + c0];
        float lf = lcf[j];
        lcv0 += wv.x * lf; lcv1 += wv.y * lf; lcv2 += wv.z * lf; lcv3 += wv.w * lf;
    }
    float acc[4][8];
#pragma unroll
    for (int kk = 0; kk < 8; ++kk) {
        acc[0][kk] = lcv0; acc[1][kk] = lcv1; acc[2][kk] = lcv2; acc[3][kk] = lcv3;
    }
    for (int j0 = 0; j0 < 128; j0 += 4) {
        float4 w0 = *(const float4*)&wt[(j0 + 0) * OD_ + c0];
        float4 w1 = *(const float4*)&wt[(j0 + 1) * OD_ + c0];
        float4 w2 = *(const float4*)&wt[(j0 + 2) * OD_ + c0];
        float4 w3 = *(const float4*)&wt[(j0 + 3) * OD_ + c0];
#pragma unroll
        for (int kk = 0; kk < 8; ++kk) {
            float4 e = *(const float4*)&E[k0 + kk][j0];
            acc[0][kk] += w0.x * e.x + w1.x * e.y + w2.x * e.z + w3.x * e.w;
            acc[1][kk] += w0.y * e.x + w1.y * e.y + w2.y * e.z + w3.y * e.w;
            acc[2][kk] += w0.z * e.x + w1.z * e.y + w2.z * e.z + w3.z * e.w;
            acc[3][kk] += w0.w * e.x + w1.w * e.y + w2.w * e.z + w3.w * e.w;
        }
    }
    for (int j = 128; j < 131; ++j) {   // xyz tail
        float wv0 = wt[j * OD_ + c0], wv1 = wt[j * OD_ + c0 + 1];
        float wv2 = wt[j * OD_ + c0 + 2], wv3 = wt[j * OD_ + c0 + 3];
#pragma unroll
        for (int kk = 0; kk < 8; ++kk) {
            float e = E[k0 + kk][j];
            acc[0][kk] += wv0 * e; acc[1][kk] += wv1 * e;
            acc[2][kk] += wv2 * e; acc[3][kk] += wv3 * e;
        }
    }
    __syncthreads();   // E + lcf reads done before xls/ebuf are overwritten
#pragma unroll
    for (int cc = 0; cc < 4; ++cc) {
        float gg = g_lin1[c0 + cc], bb = be_lin1[c0 + cc];
        float v0, v1;
#pragma unroll
        for (int kk = 0; kk < 8; kk += 2) {
            v0 = fmaxf(acc[cc][kk]     * s_bn * gg + bb, 0.f) * wk[k0 + kk];
            v1 = fmaxf(acc[cc][kk + 1] * s_bn * gg + bb, 0.f) * wk[k0 + kk + 1];
            *(float2*)&xls[c0 + cc][k0 + kk] = make_float2(v0, v1);
        }
    }
    __syncthreads();

    // ---- residual blocks
    for (int l = 0; l < 2; ++l) {
        // down: h[m][k] = relu(bn(dw @ x + db)), thread owns 4 m x 4 k
        int m0 = (tid & 31) * 4, kq0 = (tid >> 5) * 4;
        float hacc[4][4];
#pragma unroll
        for (int mm = 0; mm < 4; ++mm)
#pragma unroll
            for (int kk = 0; kk < 4; ++kk) hacc[mm][kk] = 0.f;
        const float* dw = dwt + l * (OD_ * MD_);
        for (int j = 0; j < OD_; ++j) {
            float4 wv = *(const float4*)&dw[j * MD_ + m0];
            float2 xv0 = *(const float2*)&xls[j][kq0];
            float2 xv1 = *(const float2*)&xls[j][kq0 + 2];
            hacc[0][0] += wv.x * xv0.x; hacc[0][1] += wv.x * xv0.y; hacc[0][2] += wv.x * xv1.x; hacc[0][3] += wv.x * xv1.y;
            hacc[1][0] += wv.y * xv0.x; hacc[1][1] += wv.y * xv0.y; hacc[1][2] += wv.y * xv1.x; hacc[1][3] += wv.y * xv1.y;
            hacc[2][0] += wv.z * xv0.x; hacc[2][1] += wv.z * xv0.y; hacc[2][2] += wv.z * xv1.x; hacc[2][3] += wv.z * xv1.y;
            hacc[3][0] += wv.w * xv0.x; hacc[3][1] += wv.w * xv0.y; hacc[3][2] += wv.w * xv1.x; hacc[3][3] += wv.w * xv1.y;
        }
#pragma unroll
        for (int mm = 0; mm < 4; ++mm) {
            float db = down_b[l * MD_ + m0 + mm];
            float gv = gd[l * MD_ + m0 + mm], bv2 = bd[l * MD_ + m0 + mm];
            float h0 = fmaxf((hacc[mm][0] + db) * s_bn * gv + bv2, 0.f);
            float h1 = fmaxf((hacc[mm][1] + db) * s_bn * gv + bv2, 0.f);
            float h2 = fmaxf((hacc[mm][2] + db) * s_bn * gv + bv2, 0.f);
            float h3 = fmaxf((hacc[mm][3] + db) * s_bn * gv + bv2, 0.f);
            *(float2*)&hls[m0 + mm][kq0]     = make_float2(h0, h1);
            *(float2*)&hls[m0 + mm][kq0 + 2] = make_float2(h2, h3);
        }
        __syncthreads();
        // up: o[c][k] = bn(uw @ h + ub); x = relu(o + x); thread owns 4 c x 8 k
        float uacc[4][8];
#pragma unroll
        for (int cc = 0; cc < 4; ++cc)
#pragma unroll
            for (int kk = 0; kk < 8; ++kk) uacc[cc][kk] = 0.f;
        const float* uw = uwt + l * (MD_ * OD_);
        for (int j = 0; j < MD_; ++j) {
            float4 wv = *(const float4*)&uw[j * OD_ + c0];
            float2 h0 = *(const float2*)&hls[j][k0];
            float2 h1 = *(const float2*)&hls[j][k0 + 2];
            float2 h2 = *(const float2*)&hls[j][k0 + 4];
            float2 h3 = *(const float2*)&hls[j][k0 + 6];
            uacc[0][0] += wv.x * h0.x; uacc[0][1] += wv.x * h0.y; uacc[0][2] += wv.x * h1.x; uacc[0][3] += wv.x * h1.y;
            uacc[0][4] += wv.x * h2.x; uacc[0][5] += wv.x * h2.y; uacc[0][6] += wv.x * h3.x; uacc[0][7] += wv.x * h3.y;
            uacc[1][0] += wv.y * h0.x; uacc[1][1] += wv.y * h0.y; uacc[1][2] += wv.y * h1.x; uacc[1][3] += wv.y * h1.y;
            uacc[1][4] += wv.y * h2.x; uacc[1][5] += wv.y * h2.y; uacc[1][6] += wv.y * h3.x; uacc[1][7] += wv.y * h3.y;
            uacc[2][0] += wv.z * h0.x; uacc[2][1] += wv.z * h0.y; uacc[2][2] += wv.z * h1.x; uacc[2][3] += wv.z * h1.y;
            uacc[2][4] += wv.z * h2.x; uacc[2][5] += wv.z * h2.y; uacc[2][6] += wv.z * h3.x; uacc[2][7] += wv.z * h3.y;
            uacc[3][0] += wv.w * h0.x; uacc[3][1] += wv.w * h0.y; uacc[3][2] += wv.w * h1.x; uacc[3][3] += wv.w * h1.y;
            uacc[3][4] += wv.w * h2.x; uacc[3][5] += wv.w * h2.y; uacc[3][6] += wv.w * h3.x; uacc[3][7] += wv.w * h3.y;
        }
        float nx[4][8];
#pragma unroll
        for (int cc = 0; cc < 4; ++cc) {
            float ub = up_b[l * OD_ + c0 + cc];
            float gv = gu[l * OD_ + c0 + cc], bv2 = bu[l * OD_ + c0 + cc];
#pragma unroll
            for (int kk = 0; kk < 8; ++kk) {
                float v = (uacc[cc][kk] + ub) * s_bn * gv + bv2;
                v += xls[c0 + cc][k0 + kk];
                nx[cc][kk] = fmaxf(v, 0.f);
            }
        }
        __syncthreads();
#pragma unroll
        for (int cc = 0; cc < 4; ++cc) {
            *(float2*)&xls[c0 + cc][k0]     = make_float2(nx[cc][0], nx[cc][1]);
            *(float2*)&xls[c0 + cc][k0 + 2] = make_float2(nx[cc][2], nx[cc][3]);
            *(float2*)&xls[c0 + cc][k0 + 4] = make_float2(nx[cc][4], nx[cc][5]);
            *(float2*)&xls[c0 + cc][k0 + 6] = make_float2(nx[cc][6], nx[cc][7]);
        }
        __syncthreads();
    }

    // ---- final: max_k + mean_k
    float mx = -__builtin_inff(), sm = 0.f;
#pragma unroll
    for (int k = 0; k < K_; ++k) {
        float v = xls[tid][k];
        mx = fmaxf(mx, v);
        sm += v;
    }
    out[((size_t)b * OD_ + tid) * G_ + g] = mx + sm * (1.0f / 32.0f);
}

extern "C" void kernel_launch(void* const* d_in, const int* in_sizes, int n_in,
                              void* d_out, int out_size, void* d_ws, size_t ws_size,
                              hipStream_t stream) {
    const float* xyz     = (const float*)d_in[0];
    const float* feat    = (const float*)d_in[1];
    const float* w_embed = (const float*)d_in[2];
    const float* b_embed = (const float*)d_in[3];
    const float* g_embed = (const float*)d_in[4];
    const float* be_embed= (const float*)d_in[5];
    const float* w_lin1  = (const float*)d_in[6];
    const float* g_lin1  = (const float*)d_in[7];
    const float* be_lin1 = (const float*)d_in[8];
    const float* down_w  = (const float*)d_in[9];
    const float* down_b  = (const float*)d_in[10];
    const float* gd      = (const float*)d_in[11];
    const float* bd      = (const float*)d_in[12];
    const float* up_w    = (const float*)d_in[13];
    const float* up_b    = (const float*)d_in[14];
    const float* gu      = (const float*)d_in[15];
    const float* bu      = (const float*)d_in[16];
    float* out = (float*)d_out;

    // workspace layout (~1.33 MB total)
    float* wt  = (float*)d_ws;                        // 259*256
    float* dwt = wt + OD_ * CE_;                      // 2*256*128
    float* uwt = dwt + 2 * OD_ * MD_;                 // 2*128*256
    int* sel   = (int*)(uwt + 2 * OD_ * MD_);         // 8*512
    int* nn    = sel + B_ * G_;                       // 8*512*32
    double* acc = (double*)(nn + B_ * G_ * K_);       // 2 doubles (8B aligned)
    float* stdp = (float*)(acc + 2);

    hipMemsetAsync(acc, 0, 2 * sizeof(double), stream);
    prep_kernel<<<(OD_ * CE_ + 255) / 256, 256, 0, stream>>>(w_lin1, down_w, up_w, wt, dwt, uwt);
    fps_kernel<<<B_, 1024, 0, stream>>>(xyz, sel);
    knn_kernel<<<B_ * G_, 256, 0, stream>>>(xyz, sel, nn);
    std_acc_kernel<<<256, 256, 0, stream>>>(xyz, sel, nn, acc);
    std_fin_kernel<<<1, 1, 0, stream>>>(acc, stdp);
    group_kernel<<<B_ * G_, 256, 0, stream>>>(xyz, feat, w_embed, b_embed, g_embed, be_embed,
        sel, nn, wt, dwt, uwt, g_lin1, be_lin1, down_b, gd, bd, up_b, gu, bu, stdp, out);
}

// Round 5
// 1428.924 us; speedup vs baseline: 1.3042x; 1.1173x over previous
//
#include <hip/hip_runtime.h>

#define B_ 8
#define N_ 8192
#define DIN_ 16
#define G_ 512
#define K_ 32
#define OD_ 256
#define PD_ 128
#define MD_ 128
#define CE_ 259
#define XST 34   // xls/hls row stride (floats): float2-aligned, low-conflict

// ---------------- prep: transpose weights for coalesced reads ----------------
__global__ void prep_kernel(const float* __restrict__ w_lin1,
                            const float* __restrict__ down_w,
                            const float* __restrict__ up_w,
                            float* __restrict__ wt,
                            float* __restrict__ dwt,
                            float* __restrict__ uwt) {
    int i = blockIdx.x * blockDim.x + threadIdx.x;
    if (i < OD_ * CE_) {                       // wt[j][c] = w_lin1[c][j]
        int c = i / CE_, j = i % CE_;
        wt[j * OD_ + c] = w_lin1[i];
    }
    if (i < 2 * MD_ * OD_) {                   // dwt[l][c][m] = down_w[l][m][c]
        int l = i / (MD_ * OD_); int r = i % (MD_ * OD_);
        int m = r / OD_, c = r % OD_;
        dwt[l * (OD_ * MD_) + c * MD_ + m] = down_w[i];
    }
    if (i < 2 * OD_ * MD_) {                   // uwt[l][m][c] = up_w[l][c][m]
        int l = i / (OD_ * MD_); int r = i % (OD_ * MD_);
        int c = r / MD_, m = r % MD_;
        uwt[l * (MD_ * OD_) + m * OD_ + c] = up_w[i];
    }
}

// ---------------- FPS: 256 threads / 4 waves, 32 pts/thread in registers ----------------
// DS-pipe traffic per iteration: 4x12 shuffle ops + 4x4 wred reads + 3x4 sx reads (~76)
// vs 16-wave version's ~300. One barrier per step; u64-key max preserves numpy tie order.
__global__ __launch_bounds__(256)
void fps_kernel(const float* __restrict__ xyz, int* __restrict__ sel) {
#pragma clang fp contract(off)
    __shared__ float sx[N_], sy[N_], sz[N_];
    __shared__ unsigned long long wred[2][4];
    int b = blockIdx.x, tid = threadIdx.x;
    const float* xb = xyz + (size_t)b * N_ * 3;
    for (int i = tid; i < N_; i += 256) {
        sx[i] = xb[i * 3]; sy[i] = xb[i * 3 + 1]; sz[i] = xb[i * 3 + 2];
    }
    __syncthreads();
    float px[32], py[32], pz[32], mind[32];
    float bv = -1.f; int bi = 0;
#pragma unroll
    for (int j = 0; j < 32; ++j) {
        int idx = tid + j * 256;
        px[j] = sx[idx]; py[j] = sy[idx]; pz[j] = sz[idx];
        mind[j] = 1e10f;
        float ss = (px[j] * px[j] + py[j] * py[j]) + pz[j] * pz[j];
        if (ss > bv) { bv = ss; bi = idx; }
    }
    unsigned long long key = ((unsigned long long)__float_as_uint(bv) << 32)
                           | (unsigned long long)(0xFFFFFFFFu - (unsigned)bi);
#pragma unroll
    for (int off = 32; off > 0; off >>= 1) {
        unsigned long long o = __shfl_xor(key, off); if (o > key) key = o;
    }
    if ((tid & 63) == 0) wred[0][tid >> 6] = key;
    __syncthreads();
    unsigned long long best = wred[0][0];
#pragma unroll
    for (int i = 1; i < 4; ++i) { unsigned long long v = wred[0][i]; if (v > best) best = v; }
    int cur = (int)(0xFFFFFFFFu - (unsigned)(best & 0xFFFFFFFFull));

    for (int it = 0; it < G_; ++it) {
        if (tid == 0) sel[b * G_ + it] = cur;
        float cx = sx[cur], cy = sy[cur], cz = sz[cur];
        bv = -1.f; bi = 0;
#pragma unroll
        for (int j = 0; j < 32; ++j) {
            float dx = px[j] - cx, dy = py[j] - cy, dz = pz[j] - cz;
            float d = (dx * dx + dy * dy) + dz * dz;
            float m = fminf(mind[j], d); mind[j] = m;
            if (m > bv) { bv = m; bi = tid + j * 256; }
        }
        key = ((unsigned long long)__float_as_uint(bv) << 32)
            | (unsigned long long)(0xFFFFFFFFu - (unsigned)bi);
#pragma unroll
        for (int off = 32; off > 0; off >>= 1) {
            unsigned long long o = __shfl_xor(key, off); if (o > key) key = o;
        }
        int pb = (it + 1) & 1;
        if ((tid & 63) == 0) wred[pb][tid >> 6] = key;
        __syncthreads();
        best = wred[pb][0];
#pragma unroll
        for (int i = 1; i < 4; ++i) { unsigned long long v = wred[pb][i]; if (v > best) best = v; }
        cur = (int)(0xFFFFFFFFu - (unsigned)(best & 0xFFFFFFFFull));
    }
}

// ---------------- KNN: strided ownership (conflict-free), one barrier per pick ----------------
__global__ __launch_bounds__(256)
void knn_kernel(const float* __restrict__ xyz, const int* __restrict__ sel,
                int* __restrict__ nn) {
#pragma clang fp contract(off)
    __shared__ float dld[N_];
    __shared__ unsigned long long wred[2][4];
    int gb = blockIdx.x; int b = gb >> 9, s = gb & (G_ - 1);
    const float* xb = xyz + (size_t)b * N_ * 3;
    int q = sel[b * G_ + s];
    float qx = xb[q * 3], qy = xb[q * 3 + 1], qz = xb[q * 3 + 2];
    float qq = (qx * qx + qy * qy) + qz * qz;
    int tid = threadIdx.x;
    const float FINF = __builtin_inff();
    float lv = FINF; int li = tid;
#pragma unroll 4
    for (int j = 0; j < 32; ++j) {
        int n = tid + j * 256;
        float rx = xb[n * 3], ry = xb[n * 3 + 1], rz = xb[n * 3 + 2];
        float rr = (rx * rx + ry * ry) + rz * rz;
        float dt = (qx * rx + qy * ry) + qz * rz;
        float d = (qq + rr) - 2.0f * dt;
        d = fmaxf(d, 0.f);
        dld[n] = d;
        if (d < lv) { lv = d; li = n; }
    }
    unsigned long long key = ((unsigned long long)__float_as_uint(lv) << 32) | (unsigned)li;
#pragma unroll
    for (int off = 32; off > 0; off >>= 1) {
        unsigned long long o = __shfl_xor(key, off); if (o < key) key = o;
    }
    if ((tid & 63) == 0) wred[0][tid >> 6] = key;
    __syncthreads();
    unsigned long long best = wred[0][0];
#pragma unroll
    for (int i = 1; i < 4; ++i) { unsigned long long v = wred[0][i]; if (v < best) best = v; }
    int win = (int)(best & 0xFFFFFFFFull);

    for (int t = 0; t < K_; ++t) {
        if (tid == 0) nn[(size_t)gb * K_ + t] = win;
        if ((win & 255) == tid) {
            dld[win] = FINF;
            lv = FINF; li = tid;
            for (int j = 0; j < 32; ++j) {
                float d = dld[tid + j * 256];
                if (d < lv) { lv = d; li = tid + j * 256; }
            }
        }
        key = ((unsigned long long)__float_as_uint(lv) << 32) | (unsigned)li;
#pragma unroll
        for (int off = 32; off > 0; off >>= 1) {
            unsigned long long o = __shfl_xor(key, off); if (o < key) key = o;
        }
        int pb = (t + 1) & 1;
        if ((tid & 63) == 0) wred[pb][tid >> 6] = key;
        __syncthreads();
        best = wred[pb][0];
#pragma unroll
        for (int i = 1; i < 4; ++i) { unsigned long long v = wred[pb][i]; if (v < best) best = v; }
        win = (int)(best & 0xFFFFFFFFull);
    }
}

// ---------------- global std (ddof=1) of rel_raw, f64 accumulation ----------------
__global__ void std_acc_kernel(const float* __restrict__ xyz, const int* __restrict__ sel,
                               const int* __restrict__ nn, double* __restrict__ acc) {
    int tot = B_ * G_ * K_;
    int stride = gridDim.x * blockDim.x;
    double ls = 0.0, lss = 0.0;
    for (int idx = blockIdx.x * blockDim.x + threadIdx.x; idx < tot; idx += stride) {
        int b = idx >> 14; int g = (idx >> 5) & (G_ - 1);
        int n = nn[idx]; int a = sel[b * G_ + g];
        const float* xb = xyz + (size_t)b * N_ * 3;
#pragma unroll
        for (int c = 0; c < 3; ++c) {
            float v = xb[n * 3 + c] - xb[a * 3 + c];
            ls += (double)v; lss += (double)v * (double)v;
        }
    }
#pragma unroll
    for (int off = 32; off > 0; off >>= 1) {
        ls += __shfl_down(ls, off); lss += __shfl_down(lss, off);
    }
    if ((threadIdx.x & 63) == 0) { atomicAdd(acc, ls); atomicAdd(acc + 1, lss); }
}

__global__ void std_fin_kernel(const double* __restrict__ acc, float* __restrict__ stdp) {
    double s = acc[0], ss = acc[1];
    double M = (double)(B_ * G_ * K_ * 3);
    double var = (ss - s * s / M) / (M - 1.0);
    stdp[0] = (float)sqrt(var) + 1e-5f;
}

// ---------------- fused per-group pipeline: embed + lin1 + 2 residual blocks + reduce ----------------
// LDS: xls 34816 + ebuf 17408 + ~700 = ~52.5 KB -> 3 blocks/CU
__global__ __launch_bounds__(256, 3)
void group_kernel(const float* __restrict__ xyz, const float* __restrict__ feat,
                  const float* __restrict__ wEg, const float* __restrict__ bE,
                  const float* __restrict__ gE, const float* __restrict__ beE,
                  const int* __restrict__ sel, const int* __restrict__ nn,
                  const float* __restrict__ wt, const float* __restrict__ dwt,
                  const float* __restrict__ uwt,
                  const float* __restrict__ g_lin1, const float* __restrict__ be_lin1,
                  const float* __restrict__ down_b, const float* __restrict__ gd,
                  const float* __restrict__ bd,
                  const float* __restrict__ up_b, const float* __restrict__ gu,
                  const float* __restrict__ bu,
                  const float* __restrict__ stdp, float* __restrict__ out) {
    __shared__ float xls[OD_][XST];     // x tile [c][k]; head doubles as embed scratch
    __shared__ float ebuf[4352];        // E (32x132) during lin1; hls (128x34) after
    __shared__ float wk[K_];
    __shared__ int nns[K_];
    __shared__ float anch[3];
    float (*E)[132]   = (float(*)[132])ebuf;
    float (*hls)[XST] = (float(*)[XST])ebuf;
    float* wEt = &xls[0][0];            // 16x128 transposed embed weights (2048 f)
    float* fL  = wEt + 2048;            // 33x16 gathered feats (544 f)
    float* lcf = fL + 544;              // 128 anchor embed

    int gb = blockIdx.x; int b = gb >> 9, g = gb & (G_ - 1);
    int tid = threadIdx.x;
    const float* xb = xyz + (size_t)b * N_ * 3;
    int a = sel[b * G_ + g];
    if (tid < K_) nns[tid] = nn[(size_t)gb * K_ + tid];
    if (tid < 3)  anch[tid] = xb[a * 3 + tid];
    __syncthreads();

    // ---- stage embed weights (transposed) + gathered feats
    for (int idx = tid; idx < DIN_ * PD_; idx += 256) {
        int i = idx >> 7, c = idx & 127;
        wEt[idx] = wEg[c * DIN_ + i];   // wEt[i][c] = w_embed[c][i]
    }
    const float* fb = feat + (size_t)b * N_ * DIN_;
    for (int idx = tid; idx < 33 * DIN_; idx += 256) {
        int k = idx >> 4, j = idx & 15;
        int n = (k < K_) ? nns[k] : a;
        fL[idx] = fb[(size_t)n * DIN_ + j];
    }
    __syncthreads();

    const float s_bn = 1.0f / sqrtf(1.0f + 1e-5f);
    // ---- on-the-fly embed: E[k][0:128] and lcf (anchor)
    for (int idx = tid; idx < 33 * PD_; idx += 256) {
        int k = idx >> 7, c = idx & 127;
        const float* f = &fL[k * DIN_];
        float acc2 = 0.f;
#pragma unroll
        for (int i = 0; i < DIN_; ++i) acc2 += wEt[i * PD_ + c] * f[i];
        acc2 = (acc2 + bE[c]) * s_bn * gE[c] + beE[c];
        acc2 = fmaxf(acc2, 0.f);
        if (k < K_) E[k][c] = acc2; else lcf[c] = acc2;
    }
    // E[k][128:131] = raw knn xyz
    for (int idx = tid; idx < K_ * 3; idx += 256) {
        int k = idx / 3, c = idx - k * 3;
        E[k][PD_ + c] = xb[nns[k] * 3 + c];
    }
    if (tid < K_) {
#pragma clang fp contract(off)
        float sd = stdp[0];
        int n = nns[tid];
        float rx = (xb[n * 3]     - anch[0]) / sd - anch[0];
        float ry = (xb[n * 3 + 1] - anch[1]) / sd - anch[1];
        float rz = (xb[n * 3 + 2] - anch[2]) / sd - anch[2];
        float nrm = sqrtf((rx * rx + ry * ry) + rz * rz);
        wk[tid] = expf(-0.5f * nrm);
    }
    __syncthreads();

    // ---- lin1: acc[c][k] = lcv[c] + sum_{j<131} wt[j][c]*E[k][j]
    int c0 = (tid & 63) * 4, k0 = (tid >> 6) * 8;
    // k-independent anchor term (cols 131..258 of expanded)
    float lcv0 = 0.f, lcv1 = 0.f, lcv2 = 0.f, lcv3 = 0.f;
    for (int j = 0; j < PD_; ++j) {
        float4 wv = *(const float4*)&wt[(131 + j) * OD_ + c0];
        float lf = lcf[j];
        lcv0 += wv.x * lf; lcv1 += wv.y * lf; lcv2 += wv.z * lf; lcv3 += wv.w * lf;
    }
    float acc[4][8];
#pragma unroll
    for (int kk = 0; kk < 8; ++kk) {
        acc[0][kk] = lcv0; acc[1][kk] = lcv1; acc[2][kk] = lcv2; acc[3][kk] = lcv3;
    }
    for (int j0 = 0; j0 < 128; j0 += 4) {
        float4 w0 = *(const float4*)&wt[(j0 + 0) * OD_ + c0];
        float4 w1 = *(const float4*)&wt[(j0 + 1) * OD_ + c0];
        float4 w2 = *(const float4*)&wt[(j0 + 2) * OD_ + c0];
        float4 w3 = *(const float4*)&wt[(j0 + 3) * OD_ + c0];
#pragma unroll
        for (int kk = 0; kk < 8; ++kk) {
            float4 e = *(const float4*)&E[k0 + kk][j0];
            acc[0][kk] += w0.x * e.x + w1.x * e.y + w2.x * e.z + w3.x * e.w;
            acc[1][kk] += w0.y * e.x + w1.y * e.y + w2.y * e.z + w3.y * e.w;
            acc[2][kk] += w0.z * e.x + w1.z * e.y + w2.z * e.z + w3.z * e.w;
            acc[3][kk] += w0.w * e.x + w1.w * e.y + w2.w * e.z + w3.w * e.w;
        }
    }
    for (int j = 128; j < 131; ++j) {   // xyz tail
        float wv0 = wt[j * OD_ + c0], wv1 = wt[j * OD_ + c0 + 1];
        float wv2 = wt[j * OD_ + c0 + 2], wv3 = wt[j * OD_ + c0 + 3];
#pragma unroll
        for (int kk = 0; kk < 8; ++kk) {
            float e = E[k0 + kk][j];
            acc[0][kk] += wv0 * e; acc[1][kk] += wv1 * e;
            acc[2][kk] += wv2 * e; acc[3][kk] += wv3 * e;
        }
    }
    __syncthreads();   // E + lcf reads done before xls/ebuf are overwritten
#pragma unroll
    for (int cc = 0; cc < 4; ++cc) {
        float gg = g_lin1[c0 + cc], bb = be_lin1[c0 + cc];
        float v0, v1;
#pragma unroll
        for (int kk = 0; kk < 8; kk += 2) {
            v0 = fmaxf(acc[cc][kk]     * s_bn * gg + bb, 0.f) * wk[k0 + kk];
            v1 = fmaxf(acc[cc][kk + 1] * s_bn * gg + bb, 0.f) * wk[k0 + kk + 1];
            *(float2*)&xls[c0 + cc][k0 + kk] = make_float2(v0, v1);
        }
    }
    __syncthreads();

    // ---- residual blocks
    for (int l = 0; l < 2; ++l) {
        // down: h[m][k] = relu(bn(dw @ x + db)), thread owns 4 m x 4 k
        int m0 = (tid & 31) * 4, kq0 = (tid >> 5) * 4;
        float hacc[4][4];
#pragma unroll
        for (int mm = 0; mm < 4; ++mm)
#pragma unroll
            for (int kk = 0; kk < 4; ++kk) hacc[mm][kk] = 0.f;
        const float* dw = dwt + l * (OD_ * MD_);
        for (int j = 0; j < OD_; ++j) {
            float4 wv = *(const float4*)&dw[j * MD_ + m0];
            float2 xv0 = *(const float2*)&xls[j][kq0];
            float2 xv1 = *(const float2*)&xls[j][kq0 + 2];
            hacc[0][0] += wv.x * xv0.x; hacc[0][1] += wv.x * xv0.y; hacc[0][2] += wv.x * xv1.x; hacc[0][3] += wv.x * xv1.y;
            hacc[1][0] += wv.y * xv0.x; hacc[1][1] += wv.y * xv0.y; hacc[1][2] += wv.y * xv1.x; hacc[1][3] += wv.y * xv1.y;
            hacc[2][0] += wv.z * xv0.x; hacc[2][1] += wv.z * xv0.y; hacc[2][2] += wv.z * xv1.x; hacc[2][3] += wv.z * xv1.y;
            hacc[3][0] += wv.w * xv0.x; hacc[3][1] += wv.w * xv0.y; hacc[3][2] += wv.w * xv1.x; hacc[3][3] += wv.w * xv1.y;
        }
#pragma unroll
        for (int mm = 0; mm < 4; ++mm) {
            float db = down_b[l * MD_ + m0 + mm];
            float gv = gd[l * MD_ + m0 + mm], bv2 = bd[l * MD_ + m0 + mm];
            float h0 = fmaxf((hacc[mm][0] + db) * s_bn * gv + bv2, 0.f);
            float h1 = fmaxf((hacc[mm][1] + db) * s_bn * gv + bv2, 0.f);
            float h2 = fmaxf((hacc[mm][2] + db) * s_bn * gv + bv2, 0.f);
            float h3 = fmaxf((hacc[mm][3] + db) * s_bn * gv + bv2, 0.f);
            *(float2*)&hls[m0 + mm][kq0]     = make_float2(h0, h1);
            *(float2*)&hls[m0 + mm][kq0 + 2] = make_float2(h2, h3);
        }
        __syncthreads();
        // up: o[c][k] = bn(uw @ h + ub); x = relu(o + x); thread owns 4 c x 8 k
        float uacc[4][8];
#pragma unroll
        for (int cc = 0; cc < 4; ++cc)
#pragma unroll
            for (int kk = 0; kk < 8; ++kk) uacc[cc][kk] = 0.f;
        const float* uw = uwt + l * (MD_ * OD_);
        for (int j = 0; j < MD_; ++j) {
            float4 wv = *(const float4*)&uw[j * OD_ + c0];
            float2 h0 = *(const float2*)&hls[j][k0];
            float2 h1 = *(const float2*)&hls[j][k0 + 2];
            float2 h2 = *(const float2*)&hls[j][k0 + 4];
            float2 h3 = *(const float2*)&hls[j][k0 + 6];
            uacc[0][0] += wv.x * h0.x; uacc[0][1] += wv.x * h0.y; uacc[0][2] += wv.x * h1.x; uacc[0][3] += wv.x * h1.y;
            uacc[0][4] += wv.x * h2.x; uacc[0][5] += wv.x * h2.y; uacc[0][6] += wv.x * h3.x; uacc[0][7] += wv.x * h3.y;
            uacc[1][0] += wv.y * h0.x; uacc[1][1] += wv.y * h0.y; uacc[1][2] += wv.y * h1.x; uacc[1][3] += wv.y * h1.y;
            uacc[1][4] += wv.y * h2.x; uacc[1][5] += wv.y * h2.y; uacc[1][6] += wv.y * h3.x; uacc[1][7] += wv.y * h3.y;
            uacc[2][0] += wv.z * h0.x; uacc[2][1] += wv.z * h0.y; uacc[2][2] += wv.z * h1.x; uacc[2][3] += wv.z * h1.y;
            uacc[2][4] += wv.z * h2.x; uacc[2][5] += wv.z * h2.y; uacc[2][6] += wv.z * h3.x; uacc[2][7] += wv.z * h3.y;
            uacc[3][0] += wv.w * h0.x; uacc[3][1] += wv.w * h0.y; uacc[3][2] += wv.w * h1.x; uacc[3][3] += wv.w * h1.y;
            uacc[3][4] += wv.w * h2.x; uacc[3][5] += wv.w * h2.y; uacc[3][6] += wv.w * h3.x; uacc[3][7] += wv.w * h3.y;
        }
        float nx[4][8];
#pragma unroll
        for (int cc = 0; cc < 4; ++cc) {
            float ub = up_b[l * OD_ + c0 + cc];
            float gv = gu[l * OD_ + c0 + cc], bv2 = bu[l * OD_ + c0 + cc];
#pragma unroll
            for (int kk = 0; kk < 8; ++kk) {
                float v = (uacc[cc][kk] + ub) * s_bn * gv + bv2;
                v += xls[c0 + cc][k0 + kk];
                nx[cc][kk] = fmaxf(v, 0.f);
            }
        }
        __syncthreads();
#pragma unroll
        for (int cc = 0; cc < 4; ++cc) {
            *(float2*)&xls[c0 + cc][k0]     = make_float2(nx[cc][0], nx[cc][1]);
            *(float2*)&xls[c0 + cc][k0 + 2] = make_float2(nx[cc][2], nx[cc][3]);
            *(float2*)&xls[c0 + cc][k0 + 4] = make_float2(nx[cc][4], nx[cc][5]);
            *(float2*)&xls[c0 + cc][k0 + 6] = make_float2(nx[cc][6], nx[cc][7]);
        }
        __syncthreads();
    }

    // ---- final: max_k + mean_k
    float mx = -__builtin_inff(), sm = 0.f;
#pragma unroll
    for (int k = 0; k < K_; ++k) {
        float v = xls[tid][k];
        mx = fmaxf(mx, v);
        sm += v;
    }
    out[((size_t)b * OD_ + tid) * G_ + g] = mx + sm * (1.0f / 32.0f);
}

extern "C" void kernel_launch(void* const* d_in, const int* in_sizes, int n_in,
                              void* d_out, int out_size, void* d_ws, size_t ws_size,
                              hipStream_t stream) {
    const float* xyz     = (const float*)d_in[0];
    const float* feat    = (const float*)d_in[1];
    const float* w_embed = (const float*)d_in[2];
    const float* b_embed = (const float*)d_in[3];
    const float* g_embed = (const float*)d_in[4];
    const float* be_embed= (const float*)d_in[5];
    const float* w_lin1  = (const float*)d_in[6];
    const float* g_lin1  = (const float*)d_in[7];
    const float* be_lin1 = (const float*)d_in[8];
    const float* down_w  = (const float*)d_in[9];
    const float* down_b  = (const float*)d_in[10];
    const float* gd      = (const float*)d_in[11];
    const float* bd      = (const float*)d_in[12];
    const float* up_w    = (const float*)d_in[13];
    const float* up_b    = (const float*)d_in[14];
    const float* gu      = (const float*)d_in[15];
    const float* bu      = (const float*)d_in[16];
    float* out = (float*)d_out;

    // workspace layout (~1.33 MB total)
    float* wt  = (float*)d_ws;                        // 259*256
    float* dwt = wt + OD_ * CE_;                      // 2*256*128
    float* uwt = dwt + 2 * OD_ * MD_;                 // 2*128*256
    int* sel   = (int*)(uwt + 2 * OD_ * MD_);         // 8*512
    int* nn    = sel + B_ * G_;                       // 8*512*32
    double* acc = (double*)(nn + B_ * G_ * K_);       // 2 doubles (8B aligned)
    float* stdp = (float*)(acc + 2);

    hipMemsetAsync(acc, 0, 2 * sizeof(double), stream);
    prep_kernel<<<(OD_ * CE_ + 255) / 256, 256, 0, stream>>>(w_lin1, down_w, up_w, wt, dwt, uwt);
    fps_kernel<<<B_, 256, 0, stream>>>(xyz, sel);
    knn_kernel<<<B_ * G_, 256, 0, stream>>>(xyz, sel, nn);
    std_acc_kernel<<<256, 256, 0, stream>>>(xyz, sel, nn, acc);
    std_fin_kernel<<<1, 1, 0, stream>>>(acc, stdp);
    group_kernel<<<B_ * G_, 256, 0, stream>>>(xyz, feat, w_embed, b_embed, g_embed, be_embed,
        sel, nn, wt, dwt, uwt, g_lin1, be_lin1, down_b, gd, bd, up_b, gu, bu, stdp, out);
}

// Round 6
// 1160.517 us; speedup vs baseline: 1.6059x; 1.2313x over previous
//
#include <hip/hip_runtime.h>

#define B_ 8
#define N_ 8192
#define DIN_ 16
#define G_ 512
#define K_ 32
#define OD_ 256
#define PD_ 128
#define MD_ 128
#define CE_ 259
#define EST 168    // E row stride (bf16 elems), 336B: 16B-aligned, 2-way banks
#define XST2 264   // x tile row stride, 528B
#define HST 136    // h tile row stride, 272B
#define AL1K 160   // lin1 K padded 131->160

typedef __attribute__((ext_vector_type(8))) short short8t;
typedef __attribute__((ext_vector_type(4))) float f32x4;
#define MFMA16(a, b, c) __builtin_amdgcn_mfma_f32_16x16x32_bf16((a), (b), (c), 0, 0, 0)

__device__ __forceinline__ ushort bf16_rne(float x) {
    unsigned u = __float_as_uint(x);
    return (ushort)((u + 0x7FFFu + ((u >> 16) & 1u)) >> 16);
}
__device__ __forceinline__ void bf16_split(float x, ushort& h, ushort& l) {
    h = bf16_rne(x);
    float hf = __uint_as_float((unsigned)h << 16);
    l = bf16_rne(x - hf);
}

// ---------------- prep: anchor-w transpose (f32) + bf16 hi/lo weight planes ----------------
__global__ __launch_bounds__(256)
void prep_kernel(const float* __restrict__ w_lin1, const float* __restrict__ down_w,
                 const float* __restrict__ up_w,
                 float* __restrict__ wta, ushort* __restrict__ al1,
                 ushort* __restrict__ adw, ushort* __restrict__ auw) {
    int i = blockIdx.x * blockDim.x + threadIdx.x;
    if (i < PD_ * OD_) {                        // wta[j][c] = w_lin1[c][131+j]
        int j = i >> 8, c = i & 255;
        wta[i] = w_lin1[c * CE_ + 131 + j];
    }
    if (i < OD_ * AL1K) {                       // al1[m][k] (k<131 real, else 0)
        int m = i / AL1K, k = i - m * AL1K;
        float v = (k < 131) ? w_lin1[m * CE_ + k] : 0.f;
        ushort h, l; bf16_split(v, h, l);
        al1[i] = h; al1[i + OD_ * AL1K] = l;
    }
    if (i < 2 * MD_ * OD_) {                    // down_w already [l][m][k]
        ushort h, l; bf16_split(down_w[i], h, l);
        adw[i] = h; adw[i + 2 * MD_ * OD_] = l;
    }
    if (i < 2 * OD_ * MD_) {                    // up_w already [l][m][k]
        ushort h, l; bf16_split(up_w[i], h, l);
        auw[i] = h; auw[i + 2 * OD_ * MD_] = l;
    }
}

// ---------------- FPS: 256 threads / 4 waves, 32 pts/thread in registers ----------------
__global__ __launch_bounds__(256)
void fps_kernel(const float* __restrict__ xyz, int* __restrict__ sel) {
#pragma clang fp contract(off)
    __shared__ float sx[N_], sy[N_], sz[N_];
    __shared__ unsigned long long wred[2][4];
    int b = blockIdx.x, tid = threadIdx.x;
    const float* xb = xyz + (size_t)b * N_ * 3;
    for (int i = tid; i < N_; i += 256) {
        sx[i] = xb[i * 3]; sy[i] = xb[i * 3 + 1]; sz[i] = xb[i * 3 + 2];
    }
    __syncthreads();
    float px[32], py[32], pz[32], mind[32];
    float bv = -1.f; int bi = 0;
#pragma unroll
    for (int j = 0; j < 32; ++j) {
        int idx = tid + j * 256;
        px[j] = sx[idx]; py[j] = sy[idx]; pz[j] = sz[idx];
        mind[j] = 1e10f;
        float ss = (px[j] * px[j] + py[j] * py[j]) + pz[j] * pz[j];
        if (ss > bv) { bv = ss; bi = idx; }
    }
    unsigned long long key = ((unsigned long long)__float_as_uint(bv) << 32)
                           | (unsigned long long)(0xFFFFFFFFu - (unsigned)bi);
#pragma unroll
    for (int off = 32; off > 0; off >>= 1) {
        unsigned long long o = __shfl_xor(key, off); if (o > key) key = o;
    }
    if ((tid & 63) == 0) wred[0][tid >> 6] = key;
    __syncthreads();
    unsigned long long best = wred[0][0];
#pragma unroll
    for (int i = 1; i < 4; ++i) { unsigned long long v = wred[0][i]; if (v > best) best = v; }
    int cur = (int)(0xFFFFFFFFu - (unsigned)(best & 0xFFFFFFFFull));

    for (int it = 0; it < G_; ++it) {
        if (tid == 0) sel[b * G_ + it] = cur;
        float cx = sx[cur], cy = sy[cur], cz = sz[cur];
        bv = -1.f; bi = 0;
#pragma unroll
        for (int j = 0; j < 32; ++j) {
            float dx = px[j] - cx, dy = py[j] - cy, dz = pz[j] - cz;
            float d = (dx * dx + dy * dy) + dz * dz;
            float m = fminf(mind[j], d); mind[j] = m;
            if (m > bv) { bv = m; bi = tid + j * 256; }
        }
        key = ((unsigned long long)__float_as_uint(bv) << 32)
            | (unsigned long long)(0xFFFFFFFFu - (unsigned)bi);
#pragma unroll
        for (int off = 32; off > 0; off >>= 1) {
            unsigned long long o = __shfl_xor(key, off); if (o > key) key = o;
        }
        int pb = (it + 1) & 1;
        if ((tid & 63) == 0) wred[pb][tid >> 6] = key;
        __syncthreads();
        best = wred[pb][0];
#pragma unroll
        for (int i = 1; i < 4; ++i) { unsigned long long v = wred[pb][i]; if (v > best) best = v; }
        cur = (int)(0xFFFFFFFFu - (unsigned)(best & 0xFFFFFFFFull));
    }
}

// ---------------- KNN ----------------
__global__ __launch_bounds__(256)
void knn_kernel(const float* __restrict__ xyz, const int* __restrict__ sel,
                int* __restrict__ nn) {
#pragma clang fp contract(off)
    __shared__ float dld[N_];
    __shared__ unsigned long long wred[2][4];
    int gb = blockIdx.x; int b = gb >> 9, s = gb & (G_ - 1);
    const float* xb = xyz + (size_t)b * N_ * 3;
    int q = sel[b * G_ + s];
    float qx = xb[q * 3], qy = xb[q * 3 + 1], qz = xb[q * 3 + 2];
    float qq = (qx * qx + qy * qy) + qz * qz;
    int tid = threadIdx.x;
    const float FINF = __builtin_inff();
    float lv = FINF; int li = tid;
#pragma unroll 4
    for (int j = 0; j < 32; ++j) {
        int n = tid + j * 256;
        float rx = xb[n * 3], ry = xb[n * 3 + 1], rz = xb[n * 3 + 2];
        float rr = (rx * rx + ry * ry) + rz * rz;
        float dt = (qx * rx + qy * ry) + qz * rz;
        float d = (qq + rr) - 2.0f * dt;
        d = fmaxf(d, 0.f);
        dld[n] = d;
        if (d < lv) { lv = d; li = n; }
    }
    unsigned long long key = ((unsigned long long)__float_as_uint(lv) << 32) | (unsigned)li;
#pragma unroll
    for (int off = 32; off > 0; off >>= 1) {
        unsigned long long o = __shfl_xor(key, off); if (o < key) key = o;
    }
    if ((tid & 63) == 0) wred[0][tid >> 6] = key;
    __syncthreads();
    unsigned long long best = wred[0][0];
#pragma unroll
    for (int i = 1; i < 4; ++i) { unsigned long long v = wred[0][i]; if (v < best) best = v; }
    int win = (int)(best & 0xFFFFFFFFull);

    for (int t = 0; t < K_; ++t) {
        if (tid == 0) nn[(size_t)gb * K_ + t] = win;
        if ((win & 255) == tid) {
            dld[win] = FINF;
            lv = FINF; li = tid;
            for (int j = 0; j < 32; ++j) {
                float d = dld[tid + j * 256];
                if (d < lv) { lv = d; li = tid + j * 256; }
            }
        }
        key = ((unsigned long long)__float_as_uint(lv) << 32) | (unsigned)li;
#pragma unroll
        for (int off = 32; off > 0; off >>= 1) {
            unsigned long long o = __shfl_xor(key, off); if (o < key) key = o;
        }
        int pb = (t + 1) & 1;
        if ((tid & 63) == 0) wred[pb][tid >> 6] = key;
        __syncthreads();
        best = wred[pb][0];
#pragma unroll
        for (int i = 1; i < 4; ++i) { unsigned long long v = wred[pb][i]; if (v < best) best = v; }
        win = (int)(best & 0xFFFFFFFFull);
    }
}

// ---------------- global std (ddof=1) ----------------
__global__ void std_acc_kernel(const float* __restrict__ xyz, const int* __restrict__ sel,
                               const int* __restrict__ nn, double* __restrict__ acc) {
    int tot = B_ * G_ * K_;
    int stride = gridDim.x * blockDim.x;
    double ls = 0.0, lss = 0.0;
    for (int idx = blockIdx.x * blockDim.x + threadIdx.x; idx < tot; idx += stride) {
        int b = idx >> 14; int g = (idx >> 5) & (G_ - 1);
        int n = nn[idx]; int a = sel[b * G_ + g];
        const float* xb = xyz + (size_t)b * N_ * 3;
#pragma unroll
        for (int c = 0; c < 3; ++c) {
            float v = xb[n * 3 + c] - xb[a * 3 + c];
            ls += (double)v; lss += (double)v * (double)v;
        }
    }
#pragma unroll
    for (int off = 32; off > 0; off >>= 1) {
        ls += __shfl_down(ls, off); lss += __shfl_down(lss, off);
    }
    if ((threadIdx.x & 63) == 0) { atomicAdd(acc, ls); atomicAdd(acc + 1, lss); }
}

__global__ void std_fin_kernel(const double* __restrict__ acc, float* __restrict__ stdp) {
    double s = acc[0], ss = acc[1];
    double M = (double)(B_ * G_ * K_ * 3);
    double var = (ss - s * s / M) / (M - 1.0);
    stdp[0] = (float)sqrt(var) + 1e-5f;
}

// ---------------- fused per-group pipeline, MFMA split-bf16 GEMMs ----------------
// LDS: XT 33792B + (E|HT) 17408..21504B overlay handled via XT-alias for E and
// separate HT region: smem 51200B + ~1.3KB -> 3 blocks/CU.
__global__ __launch_bounds__(256, 3)
void group_kernel(const float* __restrict__ xyz, const float* __restrict__ feat,
                  const float* __restrict__ wEg, const float* __restrict__ bE,
                  const float* __restrict__ gE, const float* __restrict__ beE,
                  const int* __restrict__ sel, const int* __restrict__ nn,
                  const float* __restrict__ wta,
                  const ushort* __restrict__ al1, const ushort* __restrict__ adw,
                  const ushort* __restrict__ auw,
                  const float* __restrict__ g_lin1, const float* __restrict__ be_lin1,
                  const float* __restrict__ down_b, const float* __restrict__ gd,
                  const float* __restrict__ bd,
                  const float* __restrict__ up_b, const float* __restrict__ gu,
                  const float* __restrict__ bu,
                  const float* __restrict__ stdp, float* __restrict__ out) {
    __shared__ __align__(16) ushort smem[25600];
    __shared__ float lcv_s[OD_];
    __shared__ float wk_s[K_];
    __shared__ int nns_s[K_];
    __shared__ float anch[3];
    ushort* XTh = smem;                 // 32 x 264
    ushort* XTl = smem + 8448;
    ushort* HTh = smem + 16896;         // 32 x 136
    ushort* HTl = smem + 21248;
    ushort* Ehi = XTh;                  // 32 x 168 (aliases XT; barrier-separated)
    ushort* Elo = XTl;
    float* wEt = (float*)(smem + 16896); // embed scratch aliases HT region
    float* fL  = wEt + 2048;
    float* lcf = fL + 544;

    int gb = blockIdx.x; int b = gb >> 9, g = gb & (G_ - 1);
    int tid = threadIdx.x;
    const float* xb = xyz + (size_t)b * N_ * 3;
    int a = sel[b * G_ + g];
    if (tid < K_) nns_s[tid] = nn[(size_t)gb * K_ + tid];
    if (tid < 3)  anch[tid] = xb[a * 3 + tid];
    __syncthreads();

    // ---- stage embed weights (transposed) + gathered feats
    for (int idx = tid; idx < DIN_ * PD_; idx += 256) {
        int i = idx >> 7, c = idx & 127;
        wEt[idx] = wEg[c * DIN_ + i];
    }
    const float* fb = feat + (size_t)b * N_ * DIN_;
    for (int idx = tid; idx < 33 * DIN_; idx += 256) {
        int k = idx >> 4, j = idx & 15;
        int n = (k < K_) ? nns_s[k] : a;
        fL[idx] = fb[(size_t)n * DIN_ + j];
    }
    __syncthreads();

    const float s_bn = 1.0f / sqrtf(1.0f + 1e-5f);
    // ---- embed -> E (split bf16), anchor -> lcf (f32)
    for (int idx = tid; idx < 33 * PD_; idx += 256) {
        int k = idx >> 7, c = idx & 127;
        const float* f = &fL[k * DIN_];
        float acc2 = 0.f;
#pragma unroll
        for (int i = 0; i < DIN_; ++i) acc2 += wEt[i * PD_ + c] * f[i];
        acc2 = (acc2 + bE[c]) * s_bn * gE[c] + beE[c];
        acc2 = fmaxf(acc2, 0.f);
        if (k < K_) { ushort h, l; bf16_split(acc2, h, l); Ehi[k * EST + c] = h; Elo[k * EST + c] = l; }
        else lcf[c] = acc2;
    }
    // E cols 128..159: knn xyz (128..130) + zero pad
    for (int idx = tid; idx < K_ * 32; idx += 256) {
        int k = idx >> 5, c = 128 + (idx & 31);
        ushort h = 0, l = 0;
        if (c < 131) { float v = xb[nns_s[k] * 3 + (c - 128)]; bf16_split(v, h, l); }
        Ehi[k * EST + c] = h; Elo[k * EST + c] = l;
    }
    if (tid < K_) {
#pragma clang fp contract(off)
        float sd = stdp[0];
        int n = nns_s[tid];
        float rx = (xb[n * 3]     - anch[0]) / sd - anch[0];
        float ry = (xb[n * 3 + 1] - anch[1]) / sd - anch[1];
        float rz = (xb[n * 3 + 2] - anch[2]) / sd - anch[2];
        float nrm = sqrtf((rx * rx + ry * ry) + rz * rz);
        wk_s[tid] = expf(-0.5f * nrm);
    }
    __syncthreads();
    // ---- anchor-term (f32 exact): lcv[c] = sum_j wta[j][c]*lcf[j]
    {
        float s = 0.f;
        for (int j = 0; j < PD_; ++j) s += wta[j * OD_ + tid] * lcf[j];
        lcv_s[tid] = s;
    }
    __syncthreads();

    int wv = tid >> 6, lane = tid & 63;
    int g16 = lane >> 4, r16 = lane & 15;

    // ---- lin1: 4 mtiles x 2 ntiles per wave, K=160, split-3 bf16
    f32x4 accl[4][2];
#pragma unroll
    for (int mt = 0; mt < 4; ++mt) {
        int mc = 64 * wv + 16 * mt + 4 * g16;
        float4 lv = *(const float4*)&lcv_s[mc];
        f32x4 iv = {lv.x, lv.y, lv.z, lv.w};
        accl[mt][0] = iv; accl[mt][1] = iv;
    }
    {
        int eb0 = r16 * EST + g16 * 8;
        int eb1 = (r16 + 16) * EST + g16 * 8;
        for (int kb = 0; kb < AL1K; kb += 32) {
            short8t eh0 = *(const short8t*)&Ehi[eb0 + kb];
            short8t el0 = *(const short8t*)&Elo[eb0 + kb];
            short8t eh1 = *(const short8t*)&Ehi[eb1 + kb];
            short8t el1 = *(const short8t*)&Elo[eb1 + kb];
#pragma unroll
            for (int mt = 0; mt < 4; ++mt) {
                int ma = 64 * wv + 16 * mt + r16;
                const ushort* wp = al1 + ma * AL1K + kb + g16 * 8;
                short8t wh = *(const short8t*)wp;
                short8t wl = *(const short8t*)(wp + OD_ * AL1K);
                accl[mt][0] = MFMA16(wh, eh0, accl[mt][0]);
                accl[mt][1] = MFMA16(wh, eh1, accl[mt][1]);
                accl[mt][0] = MFMA16(wh, el0, accl[mt][0]);
                accl[mt][1] = MFMA16(wh, el1, accl[mt][1]);
                accl[mt][0] = MFMA16(wl, eh0, accl[mt][0]);
                accl[mt][1] = MFMA16(wl, eh1, accl[mt][1]);
            }
        }
    }
    __syncthreads();   // all E reads complete before XT (same memory) is written
    {
        float w0 = wk_s[r16], w1 = wk_s[r16 + 16];
#pragma unroll
        for (int mt = 0; mt < 4; ++mt) {
            int mc = 64 * wv + 16 * mt + 4 * g16;
            float4 gg = *(const float4*)&g_lin1[mc];
            float4 bb = *(const float4*)&be_lin1[mc];
            float ga[4] = {gg.x, gg.y, gg.z, gg.w};
            float ba[4] = {bb.x, bb.y, bb.z, bb.w};
            ushort h0[4], l0[4], h1[4], l1[4];
#pragma unroll
            for (int r = 0; r < 4; ++r) {
                float v0 = fmaxf(accl[mt][0][r] * s_bn * ga[r] + ba[r], 0.f) * w0;
                float v1 = fmaxf(accl[mt][1][r] * s_bn * ga[r] + ba[r], 0.f) * w1;
                bf16_split(v0, h0[r], l0[r]);
                bf16_split(v1, h1[r], l1[r]);
            }
            *(ushort4*)&XTh[r16 * XST2 + mc] = make_ushort4(h0[0], h0[1], h0[2], h0[3]);
            *(ushort4*)&XTl[r16 * XST2 + mc] = make_ushort4(l0[0], l0[1], l0[2], l0[3]);
            *(ushort4*)&XTh[(r16 + 16) * XST2 + mc] = make_ushort4(h1[0], h1[1], h1[2], h1[3]);
            *(ushort4*)&XTl[(r16 + 16) * XST2 + mc] = make_ushort4(l1[0], l1[1], l1[2], l1[3]);
        }
    }
    __syncthreads();

    int xbo0 = r16 * XST2 + g16 * 8;
    int xbo1 = (r16 + 16) * XST2 + g16 * 8;
    int hbo0 = r16 * HST + g16 * 8;
    int hbo1 = (r16 + 16) * HST + g16 * 8;
    const f32x4 zz = {0.f, 0.f, 0.f, 0.f};
    const float inv_k = 1.0f / 32.0f;

    for (int l = 0; l < 2; ++l) {
        // ---- down: 2 mtiles x 2 ntiles per wave, K=256
        f32x4 accd[2][2];
        accd[0][0] = zz; accd[0][1] = zz; accd[1][0] = zz; accd[1][1] = zz;
        const ushort* dwb = adw + l * (MD_ * OD_);
        for (int kb = 0; kb < OD_; kb += 32) {
            short8t xh0 = *(const short8t*)&XTh[xbo0 + kb];
            short8t xl0 = *(const short8t*)&XTl[xbo0 + kb];
            short8t xh1 = *(const short8t*)&XTh[xbo1 + kb];
            short8t xl1 = *(const short8t*)&XTl[xbo1 + kb];
#pragma unroll
            for (int mt = 0; mt < 2; ++mt) {
                int ma = 32 * wv + 16 * mt + r16;
                const ushort* wp = dwb + ma * OD_ + kb + g16 * 8;
                short8t wh = *(const short8t*)wp;
                short8t wl = *(const short8t*)(wp + 2 * MD_ * OD_);
                accd[mt][0] = MFMA16(wh, xh0, accd[mt][0]);
                accd[mt][1] = MFMA16(wh, xh1, accd[mt][1]);
                accd[mt][0] = MFMA16(wh, xl0, accd[mt][0]);
                accd[mt][1] = MFMA16(wh, xl1, accd[mt][1]);
                accd[mt][0] = MFMA16(wl, xh0, accd[mt][0]);
                accd[mt][1] = MFMA16(wl, xh1, accd[mt][1]);
            }
        }
#pragma unroll
        for (int mt = 0; mt < 2; ++mt) {
            int mc = 32 * wv + 16 * mt + 4 * g16;
            float4 db = *(const float4*)&down_b[l * MD_ + mc];
            float4 gv = *(const float4*)&gd[l * MD_ + mc];
            float4 bv = *(const float4*)&bd[l * MD_ + mc];
            float dba[4] = {db.x, db.y, db.z, db.w};
            float gva[4] = {gv.x, gv.y, gv.z, gv.w};
            float bva[4] = {bv.x, bv.y, bv.z, bv.w};
            ushort h0[4], l0[4], h1[4], l1[4];
#pragma unroll
            for (int r = 0; r < 4; ++r) {
                float v0 = fmaxf((accd[mt][0][r] + dba[r]) * s_bn * gva[r] + bva[r], 0.f);
                float v1 = fmaxf((accd[mt][1][r] + dba[r]) * s_bn * gva[r] + bva[r], 0.f);
                bf16_split(v0, h0[r], l0[r]);
                bf16_split(v1, h1[r], l1[r]);
            }
            *(ushort4*)&HTh[r16 * HST + mc] = make_ushort4(h0[0], h0[1], h0[2], h0[3]);
            *(ushort4*)&HTl[r16 * HST + mc] = make_ushort4(l0[0], l0[1], l0[2], l0[3]);
            *(ushort4*)&HTh[(r16 + 16) * HST + mc] = make_ushort4(h1[0], h1[1], h1[2], h1[3]);
            *(ushort4*)&HTl[(r16 + 16) * HST + mc] = make_ushort4(l1[0], l1[1], l1[2], l1[3]);
        }
        __syncthreads();

        // ---- up: 4 mtiles x 2 ntiles per wave, K=128
        f32x4 accu[4][2];
#pragma unroll
        for (int mt = 0; mt < 4; ++mt) { accu[mt][0] = zz; accu[mt][1] = zz; }
        const ushort* uwb = auw + l * (OD_ * MD_);
        for (int kb = 0; kb < MD_; kb += 32) {
            short8t hh0 = *(const short8t*)&HTh[hbo0 + kb];
            short8t hl0 = *(const short8t*)&HTl[hbo0 + kb];
            short8t hh1 = *(const short8t*)&HTh[hbo1 + kb];
            short8t hl1 = *(const short8t*)&HTl[hbo1 + kb];
#pragma unroll
            for (int mt = 0; mt < 4; ++mt) {
                int ma = 64 * wv + 16 * mt + r16;
                const ushort* wp = uwb + ma * MD_ + kb + g16 * 8;
                short8t wh = *(const short8t*)wp;
                short8t wl = *(const short8t*)(wp + 2 * OD_ * MD_);
                accu[mt][0] = MFMA16(wh, hh0, accu[mt][0]);
                accu[mt][1] = MFMA16(wh, hh1, accu[mt][1]);
                accu[mt][0] = MFMA16(wh, hl0, accu[mt][0]);
                accu[mt][1] = MFMA16(wh, hl1, accu[mt][1]);
                accu[mt][0] = MFMA16(wl, hh0, accu[mt][0]);
                accu[mt][1] = MFMA16(wl, hh1, accu[mt][1]);
            }
        }
        // ---- up epilogue: residual add (x_old from XT hi+lo, lane-owned addrs)
#pragma unroll
        for (int mt = 0; mt < 4; ++mt) {
            int mc = 64 * wv + 16 * mt + 4 * g16;
            float4 ub = *(const float4*)&up_b[l * OD_ + mc];
            float4 gv = *(const float4*)&gu[l * OD_ + mc];
            float4 bv = *(const float4*)&bu[l * OD_ + mc];
            float uba[4] = {ub.x, ub.y, ub.z, ub.w};
            float gva[4] = {gv.x, gv.y, gv.z, gv.w};
            float bva[4] = {bv.x, bv.y, bv.z, bv.w};
            ushort4 xh0 = *(const ushort4*)&XTh[r16 * XST2 + mc];
            ushort4 xl0 = *(const ushort4*)&XTl[r16 * XST2 + mc];
            ushort4 xh1 = *(const ushort4*)&XTh[(r16 + 16) * XST2 + mc];
            ushort4 xl1 = *(const ushort4*)&XTl[(r16 + 16) * XST2 + mc];
            ushort xha0[4] = {xh0.x, xh0.y, xh0.z, xh0.w};
            ushort xla0[4] = {xl0.x, xl0.y, xl0.z, xl0.w};
            ushort xha1[4] = {xh1.x, xh1.y, xh1.z, xh1.w};
            ushort xla1[4] = {xl1.x, xl1.y, xl1.z, xl1.w};
            float nx0[4], nx1[4];
#pragma unroll
            for (int r = 0; r < 4; ++r) {
                float xf0 = __uint_as_float((unsigned)xha0[r] << 16) + __uint_as_float((unsigned)xla0[r] << 16);
                float xf1 = __uint_as_float((unsigned)xha1[r] << 16) + __uint_as_float((unsigned)xla1[r] << 16);
                float v0 = (accu[mt][0][r] + uba[r]) * s_bn * gva[r] + bva[r];
                float v1 = (accu[mt][1][r] + uba[r]) * s_bn * gva[r] + bva[r];
                nx0[r] = fmaxf(v0 + xf0, 0.f);
                nx1[r] = fmaxf(v1 + xf1, 0.f);
            }
            if (l == 0) {
                ushort h0[4], l0[4], h1[4], l1[4];
#pragma unroll
                for (int r = 0; r < 4; ++r) {
                    bf16_split(nx0[r], h0[r], l0[r]);
                    bf16_split(nx1[r], h1[r], l1[r]);
                }
                *(ushort4*)&XTh[r16 * XST2 + mc] = make_ushort4(h0[0], h0[1], h0[2], h0[3]);
                *(ushort4*)&XTl[r16 * XST2 + mc] = make_ushort4(l0[0], l0[1], l0[2], l0[3]);
                *(ushort4*)&XTh[(r16 + 16) * XST2 + mc] = make_ushort4(h1[0], h1[1], h1[2], h1[3]);
                *(ushort4*)&XTl[(r16 + 16) * XST2 + mc] = make_ushort4(l1[0], l1[1], l1[2], l1[3]);
            } else {
                // final: max + mean over 32 pts (16 lanes x 2 ntiles)
#pragma unroll
                for (int r = 0; r < 4; ++r) {
                    float mx = fmaxf(nx0[r], nx1[r]);
                    float sm = nx0[r] + nx1[r];
#pragma unroll
                    for (int off = 1; off < 16; off <<= 1) {
                        mx = fmaxf(mx, __shfl_xor(mx, off));
                        sm += __shfl_xor(sm, off);
                    }
                    if (r16 == 0)
                        out[((size_t)(b * OD_ + mc + r)) * G_ + g] = mx + sm * inv_k;
                }
            }
        }
        __syncthreads();
    }
}

extern "C" void kernel_launch(void* const* d_in, const int* in_sizes, int n_in,
                              void* d_out, int out_size, void* d_ws, size_t ws_size,
                              hipStream_t stream) {
    const float* xyz     = (const float*)d_in[0];
    const float* feat    = (const float*)d_in[1];
    const float* w_embed = (const float*)d_in[2];
    const float* b_embed = (const float*)d_in[3];
    const float* g_embed = (const float*)d_in[4];
    const float* be_embed= (const float*)d_in[5];
    const float* w_lin1  = (const float*)d_in[6];
    const float* g_lin1  = (const float*)d_in[7];
    const float* be_lin1 = (const float*)d_in[8];
    const float* down_w  = (const float*)d_in[9];
    const float* down_b  = (const float*)d_in[10];
    const float* gd      = (const float*)d_in[11];
    const float* bd      = (const float*)d_in[12];
    const float* up_w    = (const float*)d_in[13];
    const float* up_b    = (const float*)d_in[14];
    const float* gu      = (const float*)d_in[15];
    const float* bu      = (const float*)d_in[16];
    float* out = (float*)d_out;

    // workspace carve (~1.36 MB)
    char* w = (char*)d_ws;
    float* wta  = (float*)w;  w += PD_ * OD_ * 4;            // 131072
    ushort* al1 = (ushort*)w; w += 2 * OD_ * AL1K * 2;       // 163840
    ushort* adw = (ushort*)w; w += 2 * 2 * MD_ * OD_ * 2;    // 262144
    ushort* auw = (ushort*)w; w += 2 * 2 * OD_ * MD_ * 2;    // 262144
    int* sel    = (int*)w;    w += B_ * G_ * 4;              // 16384
    int* nn     = (int*)w;    w += B_ * G_ * K_ * 4;         // 524288
    double* acc = (double*)w; w += 16;
    float* stdp = (float*)w;

    hipMemsetAsync(acc, 0, 2 * sizeof(double), stream);
    prep_kernel<<<256, 256, 0, stream>>>(w_lin1, down_w, up_w, wta, al1, adw, auw);
    fps_kernel<<<B_, 256, 0, stream>>>(xyz, sel);
    knn_kernel<<<B_ * G_, 256, 0, stream>>>(xyz, sel, nn);
    std_acc_kernel<<<256, 256, 0, stream>>>(xyz, sel, nn, acc);
    std_fin_kernel<<<1, 1, 0, stream>>>(acc, stdp);
    group_kernel<<<B_ * G_, 256, 0, stream>>>(xyz, feat, w_embed, b_embed, g_embed, be_embed,
        sel, nn, wta, al1, adw, auw, g_lin1, be_lin1, down_b, gd, bd, up_b, gu, bu, stdp, out);
}

// Round 7
// 1137.652 us; speedup vs baseline: 1.6381x; 1.0201x over previous
//
#include <hip/hip_runtime.h>

#define B_ 8
#define N_ 8192
#define DIN_ 16
#define G_ 512
#define K_ 32
#define OD_ 256
#define PD_ 128
#define MD_ 128
#define CE_ 259
#define EST 168    // E row stride (bf16 elems)
#define XST2 264   // x tile row stride
#define HST 136    // h tile row stride
#define AL1K 160   // lin1 K padded 131->160

typedef __attribute__((ext_vector_type(8))) short short8t;
typedef __attribute__((ext_vector_type(4))) float f32x4;
#define MFMA16(a, b, c) __builtin_amdgcn_mfma_f32_16x16x32_bf16((a), (b), (c), 0, 0, 0)

__device__ __forceinline__ ushort bf16_rne(float x) {
    unsigned u = __float_as_uint(x);
    return (ushort)((u + 0x7FFFu + ((u >> 16) & 1u)) >> 16);
}
__device__ __forceinline__ void bf16_split(float x, ushort& h, ushort& l) {
    h = bf16_rne(x);
    float hf = __uint_as_float((unsigned)h << 16);
    l = bf16_rne(x - hf);
}

// ---- DPP wave64 reductions (VALU-only, no DS pipe). old=src so invalid-source
// lanes (bcast steps, rows 0..) keep their own value: max(x,x)/min(x,x) harmless.
#define DPP_STEP_MAXF(x, ctrl) { int _t = __builtin_amdgcn_update_dpp(            \
        __float_as_int(x), __float_as_int(x), (ctrl), 0xF, 0xF, false);           \
        (x) = fmaxf((x), __int_as_float(_t)); }
#define DPP_STEP_MINF(x, ctrl) { int _t = __builtin_amdgcn_update_dpp(            \
        __float_as_int(x), __float_as_int(x), (ctrl), 0xF, 0xF, false);           \
        (x) = fminf((x), __int_as_float(_t)); }
#define DPP_STEP_MINU(x, ctrl) { int _t = __builtin_amdgcn_update_dpp(            \
        (int)(x), (int)(x), (ctrl), 0xF, 0xF, false);                             \
        unsigned _u = (unsigned)_t; (x) = ((x) < _u) ? (x) : _u; }

__device__ __forceinline__ float wave_max_f32(float x) {
    DPP_STEP_MAXF(x, 0x121); DPP_STEP_MAXF(x, 0x122);   // row_ror:1,2
    DPP_STEP_MAXF(x, 0x124); DPP_STEP_MAXF(x, 0x128);   // row_ror:4,8
    DPP_STEP_MAXF(x, 0x142); DPP_STEP_MAXF(x, 0x143);   // row_bcast15,31
    return __int_as_float(__builtin_amdgcn_readlane(__float_as_int(x), 63));
}
__device__ __forceinline__ float wave_min_f32(float x) {
    DPP_STEP_MINF(x, 0x121); DPP_STEP_MINF(x, 0x122);
    DPP_STEP_MINF(x, 0x124); DPP_STEP_MINF(x, 0x128);
    DPP_STEP_MINF(x, 0x142); DPP_STEP_MINF(x, 0x143);
    return __int_as_float(__builtin_amdgcn_readlane(__float_as_int(x), 63));
}
__device__ __forceinline__ unsigned wave_min_u32(unsigned x) {
    DPP_STEP_MINU(x, 0x121); DPP_STEP_MINU(x, 0x122);
    DPP_STEP_MINU(x, 0x124); DPP_STEP_MINU(x, 0x128);
    DPP_STEP_MINU(x, 0x142); DPP_STEP_MINU(x, 0x143);
    return (unsigned)__builtin_amdgcn_readlane((int)x, 63);
}

// ---------------- prep: anchor-w transpose (f32) + bf16 hi/lo weight planes ----------------
__global__ __launch_bounds__(256)
void prep_kernel(const float* __restrict__ w_lin1, const float* __restrict__ down_w,
                 const float* __restrict__ up_w,
                 float* __restrict__ wta, ushort* __restrict__ al1,
                 ushort* __restrict__ adw, ushort* __restrict__ auw) {
    int i = blockIdx.x * blockDim.x + threadIdx.x;
    if (i < PD_ * OD_) {                        // wta[j][c] = w_lin1[c][131+j]
        int j = i >> 8, c = i & 255;
        wta[i] = w_lin1[c * CE_ + 131 + j];
    }
    if (i < OD_ * AL1K) {                       // al1[m][k] (k<131 real, else 0)
        int m = i / AL1K, k = i - m * AL1K;
        float v = (k < 131) ? w_lin1[m * CE_ + k] : 0.f;
        ushort h, l; bf16_split(v, h, l);
        al1[i] = h; al1[i + OD_ * AL1K] = l;
    }
    if (i < 2 * MD_ * OD_) {                    // down_w already [l][m][k]
        ushort h, l; bf16_split(down_w[i], h, l);
        adw[i] = h; adw[i + 2 * MD_ * OD_] = l;
    }
    if (i < 2 * OD_ * MD_) {                    // up_w already [l][m][k]
        ushort h, l; bf16_split(up_w[i], h, l);
        auw[i] = h; auw[i + 2 * OD_ * MD_] = l;
    }
}

// ---------------- FPS: 512 threads / 8 waves, 16 pts/thread, DPP reductions ----------------
__global__ __launch_bounds__(512)
void fps_kernel(const float* __restrict__ xyz, int* __restrict__ sel) {
#pragma clang fp contract(off)
    __shared__ float sx[N_], sy[N_], sz[N_];
    __shared__ unsigned long long wred[2][8];
    int b = blockIdx.x, tid = threadIdx.x;
    const float* xb = xyz + (size_t)b * N_ * 3;
    for (int i = tid; i < N_; i += 512) {
        sx[i] = xb[i * 3]; sy[i] = xb[i * 3 + 1]; sz[i] = xb[i * 3 + 2];
    }
    __syncthreads();
    float px[16], py[16], pz[16], mind[16];
    float bv = -1.f; int bi = 0;
#pragma unroll
    for (int j = 0; j < 16; ++j) {
        int idx = tid + j * 512;
        px[j] = sx[idx]; py[j] = sy[idx]; pz[j] = sz[idx];
        mind[j] = 1e10f;
        float ss = (px[j] * px[j] + py[j] * py[j]) + pz[j] * pz[j];
        if (ss > bv) { bv = ss; bi = idx; }
    }
    int wv = tid >> 6;
    {
        float wm = wave_max_f32(bv);
        unsigned mi = (bv == wm) ? (unsigned)bi : 0xFFFFFFFFu;
        unsigned wi = wave_min_u32(mi);
        if ((tid & 63) == 0)
            wred[0][wv] = ((unsigned long long)__float_as_uint(wm) << 32)
                        | (unsigned long long)(0xFFFFFFFFu - wi);
    }
    __syncthreads();
    unsigned long long best = wred[0][0];
#pragma unroll
    for (int i = 1; i < 8; ++i) { unsigned long long v = wred[0][i]; if (v > best) best = v; }
    int cur = (int)(0xFFFFFFFFu - (unsigned)(best & 0xFFFFFFFFull));

    for (int it = 0; it < G_; ++it) {
        if (tid == 0) sel[b * G_ + it] = cur;
        float cx = sx[cur], cy = sy[cur], cz = sz[cur];
        bv = -1.f; bi = 0;
#pragma unroll
        for (int j = 0; j < 16; ++j) {
            float dx = px[j] - cx, dy = py[j] - cy, dz = pz[j] - cz;
            float d = (dx * dx + dy * dy) + dz * dz;
            float m = fminf(mind[j], d); mind[j] = m;
            if (m > bv) { bv = m; bi = tid + j * 512; }
        }
        float wm = wave_max_f32(bv);
        unsigned mi = (bv == wm) ? (unsigned)bi : 0xFFFFFFFFu;
        unsigned wi = wave_min_u32(mi);
        int pb = (it + 1) & 1;
        if ((tid & 63) == 0)
            wred[pb][wv] = ((unsigned long long)__float_as_uint(wm) << 32)
                         | (unsigned long long)(0xFFFFFFFFu - wi);
        __syncthreads();
        best = wred[pb][0];
#pragma unroll
        for (int i = 1; i < 8; ++i) { unsigned long long v = wred[pb][i]; if (v > best) best = v; }
        cur = (int)(0xFFFFFFFFu - (unsigned)(best & 0xFFFFFFFFull));
    }
}

// ---------------- KNN: DPP argmin reductions ----------------
__global__ __launch_bounds__(256)
void knn_kernel(const float* __restrict__ xyz, const int* __restrict__ sel,
                int* __restrict__ nn) {
#pragma clang fp contract(off)
    __shared__ float dld[N_];
    __shared__ unsigned long long wred[2][4];
    int gb = blockIdx.x; int b = gb >> 9, s = gb & (G_ - 1);
    const float* xb = xyz + (size_t)b * N_ * 3;
    int q = sel[b * G_ + s];
    float qx = xb[q * 3], qy = xb[q * 3 + 1], qz = xb[q * 3 + 2];
    float qq = (qx * qx + qy * qy) + qz * qz;
    int tid = threadIdx.x;
    const float FINF = __builtin_inff();
    float lv = FINF; int li = tid;
#pragma unroll 4
    for (int j = 0; j < 32; ++j) {
        int n = tid + j * 256;
        float rx = xb[n * 3], ry = xb[n * 3 + 1], rz = xb[n * 3 + 2];
        float rr = (rx * rx + ry * ry) + rz * rz;
        float dt = (qx * rx + qy * ry) + qz * rz;
        float d = (qq + rr) - 2.0f * dt;
        d = fmaxf(d, 0.f);
        dld[n] = d;
        if (d < lv) { lv = d; li = n; }
    }
    {
        float wm = wave_min_f32(lv);
        unsigned mi = (lv == wm) ? (unsigned)li : 0xFFFFFFFFu;
        unsigned wi = wave_min_u32(mi);
        if ((tid & 63) == 0)
            wred[0][tid >> 6] = ((unsigned long long)__float_as_uint(wm) << 32)
                              | (unsigned long long)wi;
    }
    __syncthreads();
    unsigned long long best = wred[0][0];
#pragma unroll
    for (int i = 1; i < 4; ++i) { unsigned long long v = wred[0][i]; if (v < best) best = v; }
    int win = (int)(best & 0xFFFFFFFFull);

    for (int t = 0; t < K_; ++t) {
        if (tid == 0) nn[(size_t)gb * K_ + t] = win;
        if ((win & 255) == tid) {
            dld[win] = FINF;
            lv = FINF; li = tid;
            for (int j = 0; j < 32; ++j) {
                float d = dld[tid + j * 256];
                if (d < lv) { lv = d; li = tid + j * 256; }
            }
        }
        float wm = wave_min_f32(lv);
        unsigned mi = (lv == wm) ? (unsigned)li : 0xFFFFFFFFu;
        unsigned wi = wave_min_u32(mi);
        int pb = (t + 1) & 1;
        if ((tid & 63) == 0)
            wred[pb][tid >> 6] = ((unsigned long long)__float_as_uint(wm) << 32)
                               | (unsigned long long)wi;
        __syncthreads();
        best = wred[pb][0];
#pragma unroll
        for (int i = 1; i < 4; ++i) { unsigned long long v = wred[pb][i]; if (v < best) best = v; }
        win = (int)(best & 0xFFFFFFFFull);
    }
}

// ---------------- global std (ddof=1) ----------------
__global__ void std_acc_kernel(const float* __restrict__ xyz, const int* __restrict__ sel,
                               const int* __restrict__ nn, double* __restrict__ acc) {
    int tot = B_ * G_ * K_;
    int stride = gridDim.x * blockDim.x;
    double ls = 0.0, lss = 0.0;
    for (int idx = blockIdx.x * blockDim.x + threadIdx.x; idx < tot; idx += stride) {
        int b = idx >> 14; int g = (idx >> 5) & (G_ - 1);
        int n = nn[idx]; int a = sel[b * G_ + g];
        const float* xb = xyz + (size_t)b * N_ * 3;
#pragma unroll
        for (int c = 0; c < 3; ++c) {
            float v = xb[n * 3 + c] - xb[a * 3 + c];
            ls += (double)v; lss += (double)v * (double)v;
        }
    }
#pragma unroll
    for (int off = 32; off > 0; off >>= 1) {
        ls += __shfl_down(ls, off); lss += __shfl_down(lss, off);
    }
    if ((threadIdx.x & 63) == 0) { atomicAdd(acc, ls); atomicAdd(acc + 1, lss); }
}

__global__ void std_fin_kernel(const double* __restrict__ acc, float* __restrict__ stdp) {
    double s = acc[0], ss = acc[1];
    double M = (double)(B_ * G_ * K_ * 3);
    double var = (ss - s * s / M) / (M - 1.0);
    stdp[0] = (float)sqrt(var) + 1e-5f;
}

// ---------------- fused per-group pipeline, MFMA split-bf16 GEMMs ----------------
__global__ __launch_bounds__(256, 3)
void group_kernel(const float* __restrict__ xyz, const float* __restrict__ feat,
                  const float* __restrict__ wEg, const float* __restrict__ bE,
                  const float* __restrict__ gE, const float* __restrict__ beE,
                  const int* __restrict__ sel, const int* __restrict__ nn,
                  const float* __restrict__ wta,
                  const ushort* __restrict__ al1, const ushort* __restrict__ adw,
                  const ushort* __restrict__ auw,
                  const float* __restrict__ g_lin1, const float* __restrict__ be_lin1,
                  const float* __restrict__ down_b, const float* __restrict__ gd,
                  const float* __restrict__ bd,
                  const float* __restrict__ up_b, const float* __restrict__ gu,
                  const float* __restrict__ bu,
                  const float* __restrict__ stdp, float* __restrict__ out) {
    __shared__ __align__(16) ushort smem[25600];
    __shared__ float lcv_s[OD_];
    __shared__ float wk_s[K_];
    __shared__ int nns_s[K_];
    __shared__ float anch[3];
    ushort* XTh = smem;                 // 32 x 264
    ushort* XTl = smem + 8448;
    ushort* HTh = smem + 16896;         // 32 x 136
    ushort* HTl = smem + 21248;
    ushort* Ehi = XTh;                  // 32 x 168 (aliases XT; barrier-separated)
    ushort* Elo = XTl;
    float* wEt = (float*)(smem + 16896); // embed scratch aliases HT region
    float* fL  = wEt + 2048;
    float* lcf = fL + 544;

    int gb = blockIdx.x; int b = gb >> 9, g = gb & (G_ - 1);
    int tid = threadIdx.x;
    const float* xb = xyz + (size_t)b * N_ * 3;
    int a = sel[b * G_ + g];
    if (tid < K_) nns_s[tid] = nn[(size_t)gb * K_ + tid];
    if (tid < 3)  anch[tid] = xb[a * 3 + tid];
    __syncthreads();

    // ---- stage embed weights (transposed) + gathered feats
    for (int idx = tid; idx < DIN_ * PD_; idx += 256) {
        int i = idx >> 7, c = idx & 127;
        wEt[idx] = wEg[c * DIN_ + i];
    }
    const float* fb = feat + (size_t)b * N_ * DIN_;
    for (int idx = tid; idx < 33 * DIN_; idx += 256) {
        int k = idx >> 4, j = idx & 15;
        int n = (k < K_) ? nns_s[k] : a;
        fL[idx] = fb[(size_t)n * DIN_ + j];
    }
    __syncthreads();

    const float s_bn = 1.0f / sqrtf(1.0f + 1e-5f);
    // ---- embed -> E (split bf16), anchor -> lcf (f32)
    for (int idx = tid; idx < 33 * PD_; idx += 256) {
        int k = idx >> 7, c = idx & 127;
        const float* f = &fL[k * DIN_];
        float acc2 = 0.f;
#pragma unroll
        for (int i = 0; i < DIN_; ++i) acc2 += wEt[i * PD_ + c] * f[i];
        acc2 = (acc2 + bE[c]) * s_bn * gE[c] + beE[c];
        acc2 = fmaxf(acc2, 0.f);
        if (k < K_) { ushort h, l; bf16_split(acc2, h, l); Ehi[k * EST + c] = h; Elo[k * EST + c] = l; }
        else lcf[c] = acc2;
    }
    // E cols 128..159: knn xyz (128..130) + zero pad
    for (int idx = tid; idx < K_ * 32; idx += 256) {
        int k = idx >> 5, c = 128 + (idx & 31);
        ushort h = 0, l = 0;
        if (c < 131) { float v = xb[nns_s[k] * 3 + (c - 128)]; bf16_split(v, h, l); }
        Ehi[k * EST + c] = h; Elo[k * EST + c] = l;
    }
    if (tid < K_) {
#pragma clang fp contract(off)
        float sd = stdp[0];
        int n = nns_s[tid];
        float rx = (xb[n * 3]     - anch[0]) / sd - anch[0];
        float ry = (xb[n * 3 + 1] - anch[1]) / sd - anch[1];
        float rz = (xb[n * 3 + 2] - anch[2]) / sd - anch[2];
        float nrm = sqrtf((rx * rx + ry * ry) + rz * rz);
        wk_s[tid] = expf(-0.5f * nrm);
    }
    __syncthreads();
    // ---- anchor-term (f32 exact): lcv[c] = sum_j wta[j][c]*lcf[j]
    {
        float s = 0.f;
        for (int j = 0; j < PD_; ++j) s += wta[j * OD_ + tid] * lcf[j];
        lcv_s[tid] = s;
    }
    __syncthreads();

    int wv = tid >> 6, lane = tid & 63;
    int g16 = lane >> 4, r16 = lane & 15;

    // ---- lin1: 4 mtiles x 2 ntiles per wave, K=160, split-3 bf16
    f32x4 accl[4][2];
#pragma unroll
    for (int mt = 0; mt < 4; ++mt) {
        int mc = 64 * wv + 16 * mt + 4 * g16;
        float4 lv = *(const float4*)&lcv_s[mc];
        f32x4 iv = {lv.x, lv.y, lv.z, lv.w};
        accl[mt][0] = iv; accl[mt][1] = iv;
    }
    {
        int eb0 = r16 * EST + g16 * 8;
        int eb1 = (r16 + 16) * EST + g16 * 8;
        for (int kb = 0; kb < AL1K; kb += 32) {
            short8t eh0 = *(const short8t*)&Ehi[eb0 + kb];
            short8t el0 = *(const short8t*)&Elo[eb0 + kb];
            short8t eh1 = *(const short8t*)&Ehi[eb1 + kb];
            short8t el1 = *(const short8t*)&Elo[eb1 + kb];
#pragma unroll
            for (int mt = 0; mt < 4; ++mt) {
                int ma = 64 * wv + 16 * mt + r16;
                const ushort* wp = al1 + ma * AL1K + kb + g16 * 8;
                short8t wh = *(const short8t*)wp;
                short8t wl = *(const short8t*)(wp + OD_ * AL1K);
                accl[mt][0] = MFMA16(wh, eh0, accl[mt][0]);
                accl[mt][1] = MFMA16(wh, eh1, accl[mt][1]);
                accl[mt][0] = MFMA16(wh, el0, accl[mt][0]);
                accl[mt][1] = MFMA16(wh, el1, accl[mt][1]);
                accl[mt][0] = MFMA16(wl, eh0, accl[mt][0]);
                accl[mt][1] = MFMA16(wl, eh1, accl[mt][1]);
            }
        }
    }
    __syncthreads();   // all E reads complete before XT (same memory) is written
    {
        float w0 = wk_s[r16], w1 = wk_s[r16 + 16];
#pragma unroll
        for (int mt = 0; mt < 4; ++mt) {
            int mc = 64 * wv + 16 * mt + 4 * g16;
            float4 gg = *(const float4*)&g_lin1[mc];
            float4 bb = *(const float4*)&be_lin1[mc];
            float ga[4] = {gg.x, gg.y, gg.z, gg.w};
            float ba[4] = {bb.x, bb.y, bb.z, bb.w};
            ushort h0[4], l0[4], h1[4], l1[4];
#pragma unroll
            for (int r = 0; r < 4; ++r) {
                float v0 = fmaxf(accl[mt][0][r] * s_bn * ga[r] + ba[r], 0.f) * w0;
                float v1 = fmaxf(accl[mt][1][r] * s_bn * ga[r] + ba[r], 0.f) * w1;
                bf16_split(v0, h0[r], l0[r]);
                bf16_split(v1, h1[r], l1[r]);
            }
            *(ushort4*)&XTh[r16 * XST2 + mc] = make_ushort4(h0[0], h0[1], h0[2], h0[3]);
            *(ushort4*)&XTl[r16 * XST2 + mc] = make_ushort4(l0[0], l0[1], l0[2], l0[3]);
            *(ushort4*)&XTh[(r16 + 16) * XST2 + mc] = make_ushort4(h1[0], h1[1], h1[2], h1[3]);
            *(ushort4*)&XTl[(r16 + 16) * XST2 + mc] = make_ushort4(l1[0], l1[1], l1[2], l1[3]);
        }
    }
    __syncthreads();

    int xbo0 = r16 * XST2 + g16 * 8;
    int xbo1 = (r16 + 16) * XST2 + g16 * 8;
    int hbo0 = r16 * HST + g16 * 8;
    int hbo1 = (r16 + 16) * HST + g16 * 8;
    const f32x4 zz = {0.f, 0.f, 0.f, 0.f};
    const float inv_k = 1.0f / 32.0f;

    for (int l = 0; l < 2; ++l) {
        // ---- down: 2 mtiles x 2 ntiles per wave, K=256
        f32x4 accd[2][2];
        accd[0][0] = zz; accd[0][1] = zz; accd[1][0] = zz; accd[1][1] = zz;
        const ushort* dwb = adw + l * (MD_ * OD_);
        for (int kb = 0; kb < OD_; kb += 32) {
            short8t xh0 = *(const short8t*)&XTh[xbo0 + kb];
            short8t xl0 = *(const short8t*)&XTl[xbo0 + kb];
            short8t xh1 = *(const short8t*)&XTh[xbo1 + kb];
            short8t xl1 = *(const short8t*)&XTl[xbo1 + kb];
#pragma unroll
            for (int mt = 0; mt < 2; ++mt) {
                int ma = 32 * wv + 16 * mt + r16;
                const ushort* wp = dwb + ma * OD_ + kb + g16 * 8;
                short8t wh = *(const short8t*)wp;
                short8t wl = *(const short8t*)(wp + 2 * MD_ * OD_);
                accd[mt][0] = MFMA16(wh, xh0, accd[mt][0]);
                accd[mt][1] = MFMA16(wh, xh1, accd[mt][1]);
                accd[mt][0] = MFMA16(wh, xl0, accd[mt][0]);
                accd[mt][1] = MFMA16(wh, xl1, accd[mt][1]);
                accd[mt][0] = MFMA16(wl, xh0, accd[mt][0]);
                accd[mt][1] = MFMA16(wl, xh1, accd[mt][1]);
            }
        }
#pragma unroll
        for (int mt = 0; mt < 2; ++mt) {
            int mc = 32 * wv + 16 * mt + 4 * g16;
            float4 db = *(const float4*)&down_b[l * MD_ + mc];
            float4 gv = *(const float4*)&gd[l * MD_ + mc];
            float4 bv = *(const float4*)&bd[l * MD_ + mc];
            float dba[4] = {db.x, db.y, db.z, db.w};
            float gva[4] = {gv.x, gv.y, gv.z, gv.w};
            float bva[4] = {bv.x, bv.y, bv.z, bv.w};
            ushort h0[4], l0[4], h1[4], l1[4];
#pragma unroll
            for (int r = 0; r < 4; ++r) {
                float v0 = fmaxf((accd[mt][0][r] + dba[r]) * s_bn * gva[r] + bva[r], 0.f);
                float v1 = fmaxf((accd[mt][1][r] + dba[r]) * s_bn * gva[r] + bva[r], 0.f);
                bf16_split(v0, h0[r], l0[r]);
                bf16_split(v1, h1[r], l1[r]);
            }
            *(ushort4*)&HTh[r16 * HST + mc] = make_ushort4(h0[0], h0[1], h0[2], h0[3]);
            *(ushort4*)&HTl[r16 * HST + mc] = make_ushort4(l0[0], l0[1], l0[2], l0[3]);
            *(ushort4*)&HTh[(r16 + 16) * HST + mc] = make_ushort4(h1[0], h1[1], h1[2], h1[3]);
            *(ushort4*)&HTl[(r16 + 16) * HST + mc] = make_ushort4(l1[0], l1[1], l1[2], l1[3]);
        }
        __syncthreads();

        // ---- up: 4 mtiles x 2 ntiles per wave, K=128
        f32x4 accu[4][2];
#pragma unroll
        for (int mt = 0; mt < 4; ++mt) { accu[mt][0] = zz; accu[mt][1] = zz; }
        const ushort* uwb = auw + l * (OD_ * MD_);
        for (int kb = 0; kb < MD_; kb += 32) {
            short8t hh0 = *(const short8t*)&HTh[hbo0 + kb];
            short8t hl0 = *(const short8t*)&HTl[hbo0 + kb];
            short8t hh1 = *(const short8t*)&HTh[hbo1 + kb];
            short8t hl1 = *(const short8t*)&HTl[hbo1 + kb];
#pragma unroll
            for (int mt = 0; mt < 4; ++mt) {
                int ma = 64 * wv + 16 * mt + r16;
                const ushort* wp = uwb + ma * MD_ + kb + g16 * 8;
                short8t wh = *(const short8t*)wp;
                short8t wl = *(const short8t*)(wp + 2 * OD_ * MD_);
                accu[mt][0] = MFMA16(wh, hh0, accu[mt][0]);
                accu[mt][1] = MFMA16(wh, hh1, accu[mt][1]);
                accu[mt][0] = MFMA16(wh, hl0, accu[mt][0]);
                accu[mt][1] = MFMA16(wh, hl1, accu[mt][1]);
                accu[mt][0] = MFMA16(wl, hh0, accu[mt][0]);
                accu[mt][1] = MFMA16(wl, hh1, accu[mt][1]);
            }
        }
        // ---- up epilogue: residual add (x_old from XT hi+lo, lane-owned addrs)
#pragma unroll
        for (int mt = 0; mt < 4; ++mt) {
            int mc = 64 * wv + 16 * mt + 4 * g16;
            float4 ub = *(const float4*)&up_b[l * OD_ + mc];
            float4 gv = *(const float4*)&gu[l * OD_ + mc];
            float4 bv = *(const float4*)&bu[l * OD_ + mc];
            float uba[4] = {ub.x, ub.y, ub.z, ub.w};
            float gva[4] = {gv.x, gv.y, gv.z, gv.w};
            float bva[4] = {bv.x, bv.y, bv.z, bv.w};
            ushort4 xh0 = *(const ushort4*)&XTh[r16 * XST2 + mc];
            ushort4 xl0 = *(const ushort4*)&XTl[r16 * XST2 + mc];
            ushort4 xh1 = *(const ushort4*)&XTh[(r16 + 16) * XST2 + mc];
            ushort4 xl1 = *(const ushort4*)&XTl[(r16 + 16) * XST2 + mc];
            ushort xha0[4] = {xh0.x, xh0.y, xh0.z, xh0.w};
            ushort xla0[4] = {xl0.x, xl0.y, xl0.z, xl0.w};
            ushort xha1[4] = {xh1.x, xh1.y, xh1.z, xh1.w};
            ushort xla1[4] = {xl1.x, xl1.y, xl1.z, xl1.w};
            float nx0[4], nx1[4];
#pragma unroll
            for (int r = 0; r < 4; ++r) {
                float xf0 = __uint_as_float((unsigned)xha0[r] << 16) + __uint_as_float((unsigned)xla0[r] << 16);
                float xf1 = __uint_as_float((unsigned)xha1[r] << 16) + __uint_as_float((unsigned)xla1[r] << 16);
                float v0 = (accu[mt][0][r] + uba[r]) * s_bn * gva[r] + bva[r];
                float v1 = (accu[mt][1][r] + uba[r]) * s_bn * gva[r] + bva[r];
                nx0[r] = fmaxf(v0 + xf0, 0.f);
                nx1[r] = fmaxf(v1 + xf1, 0.f);
            }
            if (l == 0) {
                ushort h0[4], l0[4], h1[4], l1[4];
#pragma unroll
                for (int r = 0; r < 4; ++r) {
                    bf16_split(nx0[r], h0[r], l0[r]);
                    bf16_split(nx1[r], h1[r], l1[r]);
                }
                *(ushort4*)&XTh[r16 * XST2 + mc] = make_ushort4(h0[0], h0[1], h0[2], h0[3]);
                *(ushort4*)&XTl[r16 * XST2 + mc] = make_ushort4(l0[0], l0[1], l0[2], l0[3]);
                *(ushort4*)&XTh[(r16 + 16) * XST2 + mc] = make_ushort4(h1[0], h1[1], h1[2], h1[3]);
                *(ushort4*)&XTl[(r16 + 16) * XST2 + mc] = make_ushort4(l1[0], l1[1], l1[2], l1[3]);
            } else {
                // final: max + mean over 32 pts (16 lanes x 2 ntiles)
#pragma unroll
                for (int r = 0; r < 4; ++r) {
                    float mx = fmaxf(nx0[r], nx1[r]);
                    float sm = nx0[r] + nx1[r];
#pragma unroll
                    for (int off = 1; off < 16; off <<= 1) {
                        mx = fmaxf(mx, __shfl_xor(mx, off));
                        sm += __shfl_xor(sm, off);
                    }
                    if (r16 == 0)
                        out[((size_t)(b * OD_ + mc + r)) * G_ + g] = mx + sm * inv_k;
                }
            }
        }
        __syncthreads();
    }
}

extern "C" void kernel_launch(void* const* d_in, const int* in_sizes, int n_in,
                              void* d_out, int out_size, void* d_ws, size_t ws_size,
                              hipStream_t stream) {
    const float* xyz     = (const float*)d_in[0];
    const float* feat    = (const float*)d_in[1];
    const float* w_embed = (const float*)d_in[2];
    const float* b_embed = (const float*)d_in[3];
    const float* g_embed = (const float*)d_in[4];
    const float* be_embed= (const float*)d_in[5];
    const float* w_lin1  = (const float*)d_in[6];
    const float* g_lin1  = (const float*)d_in[7];
    const float* be_lin1 = (const float*)d_in[8];
    const float* down_w  = (const float*)d_in[9];
    const float* down_b  = (const float*)d_in[10];
    const float* gd      = (const float*)d_in[11];
    const float* bd      = (const float*)d_in[12];
    const float* up_w    = (const float*)d_in[13];
    const float* up_b    = (const float*)d_in[14];
    const float* gu      = (const float*)d_in[15];
    const float* bu      = (const float*)d_in[16];
    float* out = (float*)d_out;

    // workspace carve (~1.36 MB)
    char* w = (char*)d_ws;
    float* wta  = (float*)w;  w += PD_ * OD_ * 4;            // 131072
    ushort* al1 = (ushort*)w; w += 2 * OD_ * AL1K * 2;       // 163840
    ushort* adw = (ushort*)w; w += 2 * 2 * MD_ * OD_ * 2;    // 262144
    ushort* auw = (ushort*)w; w += 2 * 2 * OD_ * MD_ * 2;    // 262144
    int* sel    = (int*)w;    w += B_ * G_ * 4;              // 16384
    int* nn     = (int*)w;    w += B_ * G_ * K_ * 4;         // 524288
    double* acc = (double*)w; w += 16;
    float* stdp = (float*)w;

    hipMemsetAsync(acc, 0, 2 * sizeof(double), stream);
    prep_kernel<<<256, 256, 0, stream>>>(w_lin1, down_w, up_w, wta, al1, adw, auw);
    fps_kernel<<<B_, 512, 0, stream>>>(xyz, sel);
    knn_kernel<<<B_ * G_, 256, 0, stream>>>(xyz, sel, nn);
    std_acc_kernel<<<256, 256, 0, stream>>>(xyz, sel, nn, acc);
    std_fin_kernel<<<1, 1, 0, stream>>>(acc, stdp);
    group_kernel<<<B_ * G_, 256, 0, stream>>>(xyz, feat, w_embed, b_embed, g_embed, be_embed,
        sel, nn, wta, al1, adw, auw, g_lin1, be_lin1, down_b, gd, bd, up_b, gu, bu, stdp, out);
}

// Round 8
// 1090.569 us; speedup vs baseline: 1.7089x; 1.0432x over previous
//
#include <hip/hip_runtime.h>

#define B_ 8
#define N_ 8192
#define DIN_ 16
#define G_ 512
#define K_ 32
#define OD_ 256
#define PD_ 128
#define MD_ 128
#define CE_ 259
#define EST 168    // E row stride (bf16 elems)
#define XST2 264   // x tile row stride
#define HST 136    // h tile row stride
#define AL1K 160   // lin1 K padded 131->160

typedef __attribute__((ext_vector_type(8))) short short8t;
typedef __attribute__((ext_vector_type(4))) float f32x4;
#define MFMA16(a, b, c) __builtin_amdgcn_mfma_f32_16x16x32_bf16((a), (b), (c), 0, 0, 0)

__device__ __forceinline__ ushort bf16_rne(float x) {
    unsigned u = __float_as_uint(x);
    return (ushort)((u + 0x7FFFu + ((u >> 16) & 1u)) >> 16);
}
__device__ __forceinline__ void bf16_split(float x, ushort& h, ushort& l) {
    h = bf16_rne(x);
    float hf = __uint_as_float((unsigned)h << 16);
    l = bf16_rne(x - hf);
}

// ---- DPP wave64 reductions (VALU-only)
#define DPP_STEP_MAXF(x, ctrl) { int _t = __builtin_amdgcn_update_dpp(            \
        __float_as_int(x), __float_as_int(x), (ctrl), 0xF, 0xF, false);           \
        (x) = fmaxf((x), __int_as_float(_t)); }
#define DPP_STEP_MINF(x, ctrl) { int _t = __builtin_amdgcn_update_dpp(            \
        __float_as_int(x), __float_as_int(x), (ctrl), 0xF, 0xF, false);           \
        (x) = fminf((x), __int_as_float(_t)); }
#define DPP_STEP_MINU(x, ctrl) { int _t = __builtin_amdgcn_update_dpp(            \
        (int)(x), (int)(x), (ctrl), 0xF, 0xF, false);                             \
        unsigned _u = (unsigned)_t; (x) = ((x) < _u) ? (x) : _u; }

__device__ __forceinline__ float wave_max_f32(float x) {
    DPP_STEP_MAXF(x, 0x121); DPP_STEP_MAXF(x, 0x122);
    DPP_STEP_MAXF(x, 0x124); DPP_STEP_MAXF(x, 0x128);
    DPP_STEP_MAXF(x, 0x142); DPP_STEP_MAXF(x, 0x143);
    return __int_as_float(__builtin_amdgcn_readlane(__float_as_int(x), 63));
}
__device__ __forceinline__ float wave_min_f32(float x) {
    DPP_STEP_MINF(x, 0x121); DPP_STEP_MINF(x, 0x122);
    DPP_STEP_MINF(x, 0x124); DPP_STEP_MINF(x, 0x128);
    DPP_STEP_MINF(x, 0x142); DPP_STEP_MINF(x, 0x143);
    return __int_as_float(__builtin_amdgcn_readlane(__float_as_int(x), 63));
}
__device__ __forceinline__ unsigned wave_min_u32(unsigned x) {
    DPP_STEP_MINU(x, 0x121); DPP_STEP_MINU(x, 0x122);
    DPP_STEP_MINU(x, 0x124); DPP_STEP_MINU(x, 0x128);
    DPP_STEP_MINU(x, 0x142); DPP_STEP_MINU(x, 0x143);
    return (unsigned)__builtin_amdgcn_readlane((int)x, 63);
}

// ---------------- prep: fragment-ordered bf16 hi/lo weight planes ----------------
// MFMA A-fragment: lane l = g16*16+r16 supplies row (mbase+r16), k-chunk g16*8..+7.
// Fragment layout: elem(((mtile*NKB+kbi)*64+lane)*8+j)  ->  1KB coalesced per wave load.
__global__ __launch_bounds__(256)
void prep_kernel(const float* __restrict__ w_lin1, const float* __restrict__ down_w,
                 const float* __restrict__ up_w, const float* __restrict__ w_embed,
                 float* __restrict__ wta, float* __restrict__ wEtg,
                 ushort* __restrict__ alf, ushort* __restrict__ adf,
                 ushort* __restrict__ auf) {
    int i = blockIdx.x * blockDim.x + threadIdx.x;
    if (i < PD_ * OD_) {                        // wta[j][c] = w_lin1[c][131+j]
        int j = i >> 8, c = i & 255;
        wta[i] = w_lin1[c * CE_ + 131 + j];
    }
    if (i < DIN_ * PD_) {                       // wEtg[r][c] = w_embed[c][r]
        int r = i >> 7, c = i & 127;
        wEtg[i] = w_embed[c * DIN_ + r];
    }
    if (i < 5120) {                             // alf: mtile in [0,16), kbi in [0,5)
        int lane = i & 63, t = i >> 6;
        int kbi = t % 5, mtile = t / 5;
        int m = mtile * 16 + (lane & 15), g16 = lane >> 4;
        int dst = i * 8;
#pragma unroll
        for (int j = 0; j < 8; ++j) {
            int k = kbi * 32 + g16 * 8 + j;
            float v = (k < 131) ? w_lin1[m * CE_ + k] : 0.f;
            ushort h, l; bf16_split(v, h, l);
            alf[dst + j] = h; alf[dst + j + 40960] = l;
        }
    }
    if (i < 8192) {                             // adf: t = ((l*8+mtile)*8+kbi)
        int lane = i & 63, t = i >> 6;
        int kbi = t & 7, mtile = (t >> 3) & 7, l = t >> 6;
        int m = mtile * 16 + (lane & 15), g16 = lane >> 4;
        int dst = i * 8;
#pragma unroll
        for (int j = 0; j < 8; ++j) {
            int k = kbi * 32 + g16 * 8 + j;
            float v = down_w[(l * MD_ + m) * OD_ + k];
            ushort h, lo; bf16_split(v, h, lo);
            adf[dst + j] = h; adf[dst + j + 65536] = lo;
        }
    }
    if (i < 8192) {                             // auf: t = ((l*16+mtile)*4+kbi)
        int lane = i & 63, t = i >> 6;
        int kbi = t & 3, mtile = (t >> 2) & 15, l = t >> 6;
        int m = mtile * 16 + (lane & 15), g16 = lane >> 4;
        int dst = i * 8;
#pragma unroll
        for (int j = 0; j < 8; ++j) {
            int k = kbi * 32 + g16 * 8 + j;
            float v = up_w[(l * OD_ + m) * MD_ + k];
            ushort h, lo; bf16_split(v, h, lo);
            auf[dst + j] = h; auf[dst + j + 65536] = lo;
        }
    }
}

// ---------------- FPS: 512 threads / 8 waves, tree argmax + DPP reductions ----------------
__global__ __launch_bounds__(512)
void fps_kernel(const float* __restrict__ xyz, int* __restrict__ sel) {
#pragma clang fp contract(off)
    __shared__ float sx[N_], sy[N_], sz[N_];
    __shared__ unsigned long long wred[2][8];
    int b = blockIdx.x, tid = threadIdx.x;
    const float* xb = xyz + (size_t)b * N_ * 3;
    for (int i = tid; i < N_; i += 512) {
        sx[i] = xb[i * 3]; sy[i] = xb[i * 3 + 1]; sz[i] = xb[i * 3 + 2];
    }
    __syncthreads();
    float px[16], py[16], pz[16], mind[16];
#pragma unroll
    for (int j = 0; j < 16; ++j) {
        int idx = tid + j * 512;
        px[j] = sx[idx]; py[j] = sy[idx]; pz[j] = sz[idx];
        mind[j] = 1e10f;
    }
    // initial: argmax |p|^2 (tree, first-index ties)
    float tv[16]; int tj[16];
#pragma unroll
    for (int j = 0; j < 16; ++j) {
        tv[j] = (px[j] * px[j] + py[j] * py[j]) + pz[j] * pz[j];
        tj[j] = j;
    }
#pragma unroll
    for (int s = 8; s > 0; s >>= 1)
#pragma unroll
        for (int p = 0; p < 16; p += 16 / s) {
            // combine (tv[p],tj[p]) with (tv[p+8/s...]) — rewritten below
        }
    // (explicit 4-level tree)
    float v8[8]; int j8[8];
#pragma unroll
    for (int p = 0; p < 8; ++p) { bool t = tv[2*p+1] > tv[2*p]; v8[p] = t ? tv[2*p+1] : tv[2*p]; j8[p] = t ? tj[2*p+1] : tj[2*p]; }
    float v4[4]; int j4[4];
#pragma unroll
    for (int p = 0; p < 4; ++p) { bool t = v8[2*p+1] > v8[2*p]; v4[p] = t ? v8[2*p+1] : v8[2*p]; j4[p] = t ? j8[2*p+1] : j8[2*p]; }
    float v2[2]; int j2[2];
#pragma unroll
    for (int p = 0; p < 2; ++p) { bool t = v4[2*p+1] > v4[2*p]; v2[p] = t ? v4[2*p+1] : v4[2*p]; j2[p] = t ? j4[2*p+1] : j4[2*p]; }
    bool t0 = v2[1] > v2[0];
    float bv = t0 ? v2[1] : v2[0];
    int bi = tid + (t0 ? j2[1] : j2[0]) * 512;

    int wv = tid >> 6;
    {
        float wm = wave_max_f32(bv);
        unsigned mi = (bv == wm) ? (unsigned)bi : 0xFFFFFFFFu;
        unsigned wi = wave_min_u32(mi);
        if ((tid & 63) == 0)
            wred[0][wv] = ((unsigned long long)__float_as_uint(wm) << 32)
                        | (unsigned long long)(0xFFFFFFFFu - wi);
    }
    __syncthreads();
    unsigned long long best = wred[0][0];
#pragma unroll
    for (int i = 1; i < 8; ++i) { unsigned long long v = wred[0][i]; if (v > best) best = v; }
    int cur = (int)(0xFFFFFFFFu - (unsigned)(best & 0xFFFFFFFFull));

    for (int it = 0; it < G_; ++it) {
        if (tid == 0) sel[b * G_ + it] = cur;
        float cx = sx[cur], cy = sy[cur], cz = sz[cur];
#pragma unroll
        for (int j = 0; j < 16; ++j) {
            float dx = px[j] - cx, dy = py[j] - cy, dz = pz[j] - cz;
            float d = (dx * dx + dy * dy) + dz * dz;
            float m = fminf(mind[j], d); mind[j] = m;
        }
        // tree argmax over mind (first-index ties)
#pragma unroll
        for (int p = 0; p < 8; ++p) { bool t = mind[2*p+1] > mind[2*p]; v8[p] = t ? mind[2*p+1] : mind[2*p]; j8[p] = t ? (2*p+1) : (2*p); }
#pragma unroll
        for (int p = 0; p < 4; ++p) { bool t = v8[2*p+1] > v8[2*p]; v4[p] = t ? v8[2*p+1] : v8[2*p]; j4[p] = t ? j8[2*p+1] : j8[2*p]; }
#pragma unroll
        for (int p = 0; p < 2; ++p) { bool t = v4[2*p+1] > v4[2*p]; v2[p] = t ? v4[2*p+1] : v4[2*p]; j2[p] = t ? j4[2*p+1] : j4[2*p]; }
        t0 = v2[1] > v2[0];
        bv = t0 ? v2[1] : v2[0];
        bi = tid + (t0 ? j2[1] : j2[0]) * 512;

        float wm = wave_max_f32(bv);
        unsigned mi = (bv == wm) ? (unsigned)bi : 0xFFFFFFFFu;
        unsigned wi = wave_min_u32(mi);
        int pb = (it + 1) & 1;
        if ((tid & 63) == 0)
            wred[pb][wv] = ((unsigned long long)__float_as_uint(wm) << 32)
                         | (unsigned long long)(0xFFFFFFFFu - wi);
        __syncthreads();
        best = wred[pb][0];
#pragma unroll
        for (int i = 1; i < 8; ++i) { unsigned long long v = wred[pb][i]; if (v > best) best = v; }
        cur = (int)(0xFFFFFFFFu - (unsigned)(best & 0xFFFFFFFFull));
    }
}

// ---------------- KNN: DPP argmin reductions ----------------
__global__ __launch_bounds__(256)
void knn_kernel(const float* __restrict__ xyz, const int* __restrict__ sel,
                int* __restrict__ nn) {
#pragma clang fp contract(off)
    __shared__ float dld[N_];
    __shared__ unsigned long long wred[2][4];
    int gb = blockIdx.x; int b = gb >> 9, s = gb & (G_ - 1);
    const float* xb = xyz + (size_t)b * N_ * 3;
    int q = sel[b * G_ + s];
    float qx = xb[q * 3], qy = xb[q * 3 + 1], qz = xb[q * 3 + 2];
    float qq = (qx * qx + qy * qy) + qz * qz;
    int tid = threadIdx.x;
    const float FINF = __builtin_inff();
    float lv = FINF; int li = tid;
#pragma unroll 4
    for (int j = 0; j < 32; ++j) {
        int n = tid + j * 256;
        float rx = xb[n * 3], ry = xb[n * 3 + 1], rz = xb[n * 3 + 2];
        float rr = (rx * rx + ry * ry) + rz * rz;
        float dt = (qx * rx + qy * ry) + qz * rz;
        float d = (qq + rr) - 2.0f * dt;
        d = fmaxf(d, 0.f);
        dld[n] = d;
        if (d < lv) { lv = d; li = n; }
    }
    {
        float wm = wave_min_f32(lv);
        unsigned mi = (lv == wm) ? (unsigned)li : 0xFFFFFFFFu;
        unsigned wi = wave_min_u32(mi);
        if ((tid & 63) == 0)
            wred[0][tid >> 6] = ((unsigned long long)__float_as_uint(wm) << 32)
                              | (unsigned long long)wi;
    }
    __syncthreads();
    unsigned long long best = wred[0][0];
#pragma unroll
    for (int i = 1; i < 4; ++i) { unsigned long long v = wred[0][i]; if (v < best) best = v; }
    int win = (int)(best & 0xFFFFFFFFull);

    for (int t = 0; t < K_; ++t) {
        if (tid == 0) nn[(size_t)gb * K_ + t] = win;
        if ((win & 255) == tid) {
            dld[win] = FINF;
            lv = FINF; li = tid;
            for (int j = 0; j < 32; ++j) {
                float d = dld[tid + j * 256];
                if (d < lv) { lv = d; li = tid + j * 256; }
            }
        }
        float wm = wave_min_f32(lv);
        unsigned mi = (lv == wm) ? (unsigned)li : 0xFFFFFFFFu;
        unsigned wi = wave_min_u32(mi);
        int pb = (t + 1) & 1;
        if ((tid & 63) == 0)
            wred[pb][tid >> 6] = ((unsigned long long)__float_as_uint(wm) << 32)
                               | (unsigned long long)wi;
        __syncthreads();
        best = wred[pb][0];
#pragma unroll
        for (int i = 1; i < 4; ++i) { unsigned long long v = wred[pb][i]; if (v < best) best = v; }
        win = (int)(best & 0xFFFFFFFFull);
    }
}

// ---------------- global std (ddof=1) ----------------
__global__ void std_acc_kernel(const float* __restrict__ xyz, const int* __restrict__ sel,
                               const int* __restrict__ nn, double* __restrict__ acc) {
    int tot = B_ * G_ * K_;
    int stride = gridDim.x * blockDim.x;
    double ls = 0.0, lss = 0.0;
    for (int idx = blockIdx.x * blockDim.x + threadIdx.x; idx < tot; idx += stride) {
        int b = idx >> 14; int g = (idx >> 5) & (G_ - 1);
        int n = nn[idx]; int a = sel[b * G_ + g];
        const float* xb = xyz + (size_t)b * N_ * 3;
#pragma unroll
        for (int c = 0; c < 3; ++c) {
            float v = xb[n * 3 + c] - xb[a * 3 + c];
            ls += (double)v; lss += (double)v * (double)v;
        }
    }
#pragma unroll
    for (int off = 32; off > 0; off >>= 1) {
        ls += __shfl_down(ls, off); lss += __shfl_down(lss, off);
    }
    if ((threadIdx.x & 63) == 0) { atomicAdd(acc, ls); atomicAdd(acc + 1, lss); }
}

__global__ void std_fin_kernel(const double* __restrict__ acc, float* __restrict__ stdp) {
    double s = acc[0], ss = acc[1];
    double M = (double)(B_ * G_ * K_ * 3);
    double var = (ss - s * s / M) / (M - 1.0);
    stdp[0] = (float)sqrt(var) + 1e-5f;
}

// ---------------- fused per-group pipeline, MFMA split-bf16 GEMMs ----------------
__global__ __launch_bounds__(256, 3)
void group_kernel(const float* __restrict__ xyz, const float* __restrict__ feat,
                  const float* __restrict__ wEtg, const float* __restrict__ bE,
                  const float* __restrict__ gE, const float* __restrict__ beE,
                  const int* __restrict__ sel, const int* __restrict__ nn,
                  const float* __restrict__ wta,
                  const ushort* __restrict__ alf, const ushort* __restrict__ adf,
                  const ushort* __restrict__ auf,
                  const float* __restrict__ g_lin1, const float* __restrict__ be_lin1,
                  const float* __restrict__ down_b, const float* __restrict__ gd,
                  const float* __restrict__ bd,
                  const float* __restrict__ up_b, const float* __restrict__ gu,
                  const float* __restrict__ bu,
                  const float* __restrict__ stdp, float* __restrict__ out) {
    __shared__ __align__(16) ushort smem[25600];
    __shared__ float lcv_s[OD_];
    __shared__ float wk_s[K_];
    __shared__ int nns_s[K_];
    __shared__ float anch[3];
    ushort* XTh = smem;                 // 32 x 264
    ushort* XTl = smem + 8448;
    ushort* HTh = smem + 16896;         // 32 x 136
    ushort* HTl = smem + 21248;
    ushort* Ehi = XTh;                  // 32 x 168 (aliases XT; barrier-separated)
    ushort* Elo = XTl;
    float* wEt = (float*)(smem + 16896); // embed scratch aliases HT region
    float* fL  = wEt + 2048;
    float* lcf = fL + 544;

    int gb = blockIdx.x; int b = gb >> 9, g = gb & (G_ - 1);
    int tid = threadIdx.x;
    const float* xb = xyz + (size_t)b * N_ * 3;
    int a = sel[b * G_ + g];
    if (tid < K_) nns_s[tid] = nn[(size_t)gb * K_ + tid];
    if (tid < 3)  anch[tid] = xb[a * 3 + tid];
    __syncthreads();

    // ---- stage embed weights (pre-transposed, coalesced) + gathered feats
    for (int idx = tid; idx < DIN_ * PD_; idx += 256) wEt[idx] = wEtg[idx];
    const float* fb = feat + (size_t)b * N_ * DIN_;
    for (int idx = tid; idx < 33 * DIN_; idx += 256) {
        int k = idx >> 4, j = idx & 15;
        int n = (k < K_) ? nns_s[k] : a;
        fL[idx] = fb[(size_t)n * DIN_ + j];
    }
    __syncthreads();

    const float s_bn = 1.0f / sqrtf(1.0f + 1e-5f);
    // ---- embed -> E (split bf16), anchor -> lcf (f32)
    for (int idx = tid; idx < 33 * PD_; idx += 256) {
        int k = idx >> 7, c = idx & 127;
        const float* f = &fL[k * DIN_];
        float acc2 = 0.f;
#pragma unroll
        for (int i = 0; i < DIN_; ++i) acc2 += wEt[i * PD_ + c] * f[i];
        acc2 = (acc2 + bE[c]) * s_bn * gE[c] + beE[c];
        acc2 = fmaxf(acc2, 0.f);
        if (k < K_) { ushort h, l; bf16_split(acc2, h, l); Ehi[k * EST + c] = h; Elo[k * EST + c] = l; }
        else lcf[c] = acc2;
    }
    // E cols 128..159: knn xyz (128..130) + zero pad
    for (int idx = tid; idx < K_ * 32; idx += 256) {
        int k = idx >> 5, c = 128 + (idx & 31);
        ushort h = 0, l = 0;
        if (c < 131) { float v = xb[nns_s[k] * 3 + (c - 128)]; bf16_split(v, h, l); }
        Ehi[k * EST + c] = h; Elo[k * EST + c] = l;
    }
    if (tid < K_) {
#pragma clang fp contract(off)
        float sd = stdp[0];
        int n = nns_s[tid];
        float rx = (xb[n * 3]     - anch[0]) / sd - anch[0];
        float ry = (xb[n * 3 + 1] - anch[1]) / sd - anch[1];
        float rz = (xb[n * 3 + 2] - anch[2]) / sd - anch[2];
        float nrm = sqrtf((rx * rx + ry * ry) + rz * rz);
        wk_s[tid] = expf(-0.5f * nrm);
    }
    __syncthreads();
    // ---- anchor-term (f32 exact): lcv[c] = sum_j wta[j][c]*lcf[j]
    {
        float s = 0.f;
        for (int j = 0; j < PD_; ++j) s += wta[j * OD_ + tid] * lcf[j];
        lcv_s[tid] = s;
    }
    __syncthreads();

    int wv = tid >> 6, lane = tid & 63;
    int g16 = lane >> 4, r16 = lane & 15;
    int lane8 = lane * 8;

    // ---- lin1: 4 mtiles x 2 ntiles per wave, K=160, split-3 bf16
    f32x4 accl[4][2];
#pragma unroll
    for (int mt = 0; mt < 4; ++mt) {
        int mc = 64 * wv + 16 * mt + 4 * g16;
        float4 lv = *(const float4*)&lcv_s[mc];
        f32x4 iv = {lv.x, lv.y, lv.z, lv.w};
        accl[mt][0] = iv; accl[mt][1] = iv;
    }
    {
        int eb0 = r16 * EST + g16 * 8;
        int eb1 = (r16 + 16) * EST + g16 * 8;
        for (int kbi = 0; kbi < 5; ++kbi) {
            int kb = kbi * 32;
            short8t eh0 = *(const short8t*)&Ehi[eb0 + kb];
            short8t el0 = *(const short8t*)&Elo[eb0 + kb];
            short8t eh1 = *(const short8t*)&Ehi[eb1 + kb];
            short8t el1 = *(const short8t*)&Elo[eb1 + kb];
#pragma unroll
            for (int mt = 0; mt < 4; ++mt) {
                const ushort* wp = alf + (((4 * wv + mt) * 5 + kbi) << 9) + lane8;
                short8t wh = *(const short8t*)wp;
                short8t wl = *(const short8t*)(wp + 40960);
                accl[mt][0] = MFMA16(wh, eh0, accl[mt][0]);
                accl[mt][1] = MFMA16(wh, eh1, accl[mt][1]);
                accl[mt][0] = MFMA16(wh, el0, accl[mt][0]);
                accl[mt][1] = MFMA16(wh, el1, accl[mt][1]);
                accl[mt][0] = MFMA16(wl, eh0, accl[mt][0]);
                accl[mt][1] = MFMA16(wl, eh1, accl[mt][1]);
            }
        }
    }
    __syncthreads();   // all E reads complete before XT (same memory) is written
    {
        float w0 = wk_s[r16], w1 = wk_s[r16 + 16];
#pragma unroll
        for (int mt = 0; mt < 4; ++mt) {
            int mc = 64 * wv + 16 * mt + 4 * g16;
            float4 gg = *(const float4*)&g_lin1[mc];
            float4 bb = *(const float4*)&be_lin1[mc];
            float ga[4] = {gg.x, gg.y, gg.z, gg.w};
            float ba[4] = {bb.x, bb.y, bb.z, bb.w};
            ushort h0[4], l0[4], h1[4], l1[4];
#pragma unroll
            for (int r = 0; r < 4; ++r) {
                float v0 = fmaxf(accl[mt][0][r] * s_bn * ga[r] + ba[r], 0.f) * w0;
                float v1 = fmaxf(accl[mt][1][r] * s_bn * ga[r] + ba[r], 0.f) * w1;
                bf16_split(v0, h0[r], l0[r]);
                bf16_split(v1, h1[r], l1[r]);
            }
            *(ushort4*)&XTh[r16 * XST2 + mc] = make_ushort4(h0[0], h0[1], h0[2], h0[3]);
            *(ushort4*)&XTl[r16 * XST2 + mc] = make_ushort4(l0[0], l0[1], l0[2], l0[3]);
            *(ushort4*)&XTh[(r16 + 16) * XST2 + mc] = make_ushort4(h1[0], h1[1], h1[2], h1[3]);
            *(ushort4*)&XTl[(r16 + 16) * XST2 + mc] = make_ushort4(l1[0], l1[1], l1[2], l1[3]);
        }
    }
    __syncthreads();

    int xbo0 = r16 * XST2 + g16 * 8;
    int xbo1 = (r16 + 16) * XST2 + g16 * 8;
    int hbo0 = r16 * HST + g16 * 8;
    int hbo1 = (r16 + 16) * HST + g16 * 8;
    const f32x4 zz = {0.f, 0.f, 0.f, 0.f};
    const float inv_k = 1.0f / 32.0f;

    for (int l = 0; l < 2; ++l) {
        // ---- down: 2 mtiles x 2 ntiles per wave, K=256
        f32x4 accd[2][2];
        accd[0][0] = zz; accd[0][1] = zz; accd[1][0] = zz; accd[1][1] = zz;
        for (int kbi = 0; kbi < 8; ++kbi) {
            int kb = kbi * 32;
            short8t xh0 = *(const short8t*)&XTh[xbo0 + kb];
            short8t xl0 = *(const short8t*)&XTl[xbo0 + kb];
            short8t xh1 = *(const short8t*)&XTh[xbo1 + kb];
            short8t xl1 = *(const short8t*)&XTl[xbo1 + kb];
#pragma unroll
            for (int mt = 0; mt < 2; ++mt) {
                const ushort* wp = adf + (((l * 8 + (2 * wv + mt)) * 8 + kbi) << 9) + lane8;
                short8t wh = *(const short8t*)wp;
                short8t wl = *(const short8t*)(wp + 65536);
                accd[mt][0] = MFMA16(wh, xh0, accd[mt][0]);
                accd[mt][1] = MFMA16(wh, xh1, accd[mt][1]);
                accd[mt][0] = MFMA16(wh, xl0, accd[mt][0]);
                accd[mt][1] = MFMA16(wh, xl1, accd[mt][1]);
                accd[mt][0] = MFMA16(wl, xh0, accd[mt][0]);
                accd[mt][1] = MFMA16(wl, xh1, accd[mt][1]);
            }
        }
#pragma unroll
        for (int mt = 0; mt < 2; ++mt) {
            int mc = 32 * wv + 16 * mt + 4 * g16;
            float4 db = *(const float4*)&down_b[l * MD_ + mc];
            float4 gv = *(const float4*)&gd[l * MD_ + mc];
            float4 bv = *(const float4*)&bd[l * MD_ + mc];
            float dba[4] = {db.x, db.y, db.z, db.w};
            float gva[4] = {gv.x, gv.y, gv.z, gv.w};
            float bva[4] = {bv.x, bv.y, bv.z, bv.w};
            ushort h0[4], l0[4], h1[4], l1[4];
#pragma unroll
            for (int r = 0; r < 4; ++r) {
                float v0 = fmaxf((accd[mt][0][r] + dba[r]) * s_bn * gva[r] + bva[r], 0.f);
                float v1 = fmaxf((accd[mt][1][r] + dba[r]) * s_bn * gva[r] + bva[r], 0.f);
                bf16_split(v0, h0[r], l0[r]);
                bf16_split(v1, h1[r], l1[r]);
            }
            *(ushort4*)&HTh[r16 * HST + mc] = make_ushort4(h0[0], h0[1], h0[2], h0[3]);
            *(ushort4*)&HTl[r16 * HST + mc] = make_ushort4(l0[0], l0[1], l0[2], l0[3]);
            *(ushort4*)&HTh[(r16 + 16) * HST + mc] = make_ushort4(h1[0], h1[1], h1[2], h1[3]);
            *(ushort4*)&HTl[(r16 + 16) * HST + mc] = make_ushort4(l1[0], l1[1], l1[2], l1[3]);
        }
        __syncthreads();

        // ---- up: 4 mtiles x 2 ntiles per wave, K=128
        f32x4 accu[4][2];
#pragma unroll
        for (int mt = 0; mt < 4; ++mt) { accu[mt][0] = zz; accu[mt][1] = zz; }
        for (int kbi = 0; kbi < 4; ++kbi) {
            int kb = kbi * 32;
            short8t hh0 = *(const short8t*)&HTh[hbo0 + kb];
            short8t hl0 = *(const short8t*)&HTl[hbo0 + kb];
            short8t hh1 = *(const short8t*)&HTh[hbo1 + kb];
            short8t hl1 = *(const short8t*)&HTl[hbo1 + kb];
#pragma unroll
            for (int mt = 0; mt < 4; ++mt) {
                const ushort* wp = auf + (((l * 16 + (4 * wv + mt)) * 4 + kbi) << 9) + lane8;
                short8t wh = *(const short8t*)wp;
                short8t wl = *(const short8t*)(wp + 65536);
                accu[mt][0] = MFMA16(wh, hh0, accu[mt][0]);
                accu[mt][1] = MFMA16(wh, hh1, accu[mt][1]);
                accu[mt][0] = MFMA16(wh, hl0, accu[mt][0]);
                accu[mt][1] = MFMA16(wh, hl1, accu[mt][1]);
                accu[mt][0] = MFMA16(wl, hh0, accu[mt][0]);
                accu[mt][1] = MFMA16(wl, hh1, accu[mt][1]);
            }
        }
        // ---- up epilogue: residual add
#pragma unroll
        for (int mt = 0; mt < 4; ++mt) {
            int mc = 64 * wv + 16 * mt + 4 * g16;
            float4 ub = *(const float4*)&up_b[l * OD_ + mc];
            float4 gv = *(const float4*)&gu[l * OD_ + mc];
            float4 bv = *(const float4*)&bu[l * OD_ + mc];
            float uba[4] = {ub.x, ub.y, ub.z, ub.w};
            float gva[4] = {gv.x, gv.y, gv.z, gv.w};
            float bva[4] = {bv.x, bv.y, bv.z, bv.w};
            ushort4 xh0 = *(const ushort4*)&XTh[r16 * XST2 + mc];
            ushort4 xl0 = *(const ushort4*)&XTl[r16 * XST2 + mc];
            ushort4 xh1 = *(const ushort4*)&XTh[(r16 + 16) * XST2 + mc];
            ushort4 xl1 = *(const ushort4*)&XTl[(r16 + 16) * XST2 + mc];
            ushort xha0[4] = {xh0.x, xh0.y, xh0.z, xh0.w};
            ushort xla0[4] = {xl0.x, xl0.y, xl0.z, xl0.w};
            ushort xha1[4] = {xh1.x, xh1.y, xh1.z, xh1.w};
            ushort xla1[4] = {xl1.x, xl1.y, xl1.z, xl1.w};
            float nx0[4], nx1[4];
#pragma unroll
            for (int r = 0; r < 4; ++r) {
                float xf0 = __uint_as_float((unsigned)xha0[r] << 16) + __uint_as_float((unsigned)xla0[r] << 16);
                float xf1 = __uint_as_float((unsigned)xha1[r] << 16) + __uint_as_float((unsigned)xla1[r] << 16);
                float v0 = (accu[mt][0][r] + uba[r]) * s_bn * gva[r] + bva[r];
                float v1 = (accu[mt][1][r] + uba[r]) * s_bn * gva[r] + bva[r];
                nx0[r] = fmaxf(v0 + xf0, 0.f);
                nx1[r] = fmaxf(v1 + xf1, 0.f);
            }
            if (l == 0) {
                ushort h0[4], l0[4], h1[4], l1[4];
#pragma unroll
                for (int r = 0; r < 4; ++r) {
                    bf16_split(nx0[r], h0[r], l0[r]);
                    bf16_split(nx1[r], h1[r], l1[r]);
                }
                *(ushort4*)&XTh[r16 * XST2 + mc] = make_ushort4(h0[0], h0[1], h0[2], h0[3]);
                *(ushort4*)&XTl[r16 * XST2 + mc] = make_ushort4(l0[0], l0[1], l0[2], l0[3]);
                *(ushort4*)&XTh[(r16 + 16) * XST2 + mc] = make_ushort4(h1[0], h1[1], h1[2], h1[3]);
                *(ushort4*)&XTl[(r16 + 16) * XST2 + mc] = make_ushort4(l1[0], l1[1], l1[2], l1[3]);
            } else {
                // final: max + mean over 32 pts (16 lanes x 2 ntiles)
#pragma unroll
                for (int r = 0; r < 4; ++r) {
                    float mx = fmaxf(nx0[r], nx1[r]);
                    float sm = nx0[r] + nx1[r];
#pragma unroll
                    for (int off = 1; off < 16; off <<= 1) {
                        mx = fmaxf(mx, __shfl_xor(mx, off));
                        sm += __shfl_xor(sm, off);
                    }
                    if (r16 == 0)
                        out[((size_t)(b * OD_ + mc + r)) * G_ + g] = mx + sm * inv_k;
                }
            }
        }
        __syncthreads();
    }
}

extern "C" void kernel_launch(void* const* d_in, const int* in_sizes, int n_in,
                              void* d_out, int out_size, void* d_ws, size_t ws_size,
                              hipStream_t stream) {
    const float* xyz     = (const float*)d_in[0];
    const float* feat    = (const float*)d_in[1];
    const float* w_embed = (const float*)d_in[2];
    const float* b_embed = (const float*)d_in[3];
    const float* g_embed = (const float*)d_in[4];
    const float* be_embed= (const float*)d_in[5];
    const float* w_lin1  = (const float*)d_in[6];
    const float* g_lin1  = (const float*)d_in[7];
    const float* be_lin1 = (const float*)d_in[8];
    const float* down_w  = (const float*)d_in[9];
    const float* down_b  = (const float*)d_in[10];
    const float* gd      = (const float*)d_in[11];
    const float* bd      = (const float*)d_in[12];
    const float* up_w    = (const float*)d_in[13];
    const float* up_b    = (const float*)d_in[14];
    const float* gu      = (const float*)d_in[15];
    const float* bu      = (const float*)d_in[16];
    float* out = (float*)d_out;

    // workspace carve (~1.38 MB)
    char* w = (char*)d_ws;
    float* wta   = (float*)w;  w += PD_ * OD_ * 4;           // 131072
    float* wEtg  = (float*)w;  w += DIN_ * PD_ * 4;          // 8192
    ushort* alf  = (ushort*)w; w += 2 * 40960 * 2;           // 163840
    ushort* adf  = (ushort*)w; w += 2 * 65536 * 2;           // 262144
    ushort* auf  = (ushort*)w; w += 2 * 65536 * 2;           // 262144
    int* sel     = (int*)w;    w += B_ * G_ * 4;             // 16384
    int* nn      = (int*)w;    w += B_ * G_ * K_ * 4;        // 524288
    double* acc  = (double*)w; w += 16;
    float* stdp  = (float*)w;

    hipMemsetAsync(acc, 0, 2 * sizeof(double), stream);
    prep_kernel<<<256, 256, 0, stream>>>(w_lin1, down_w, up_w, w_embed,
                                         wta, wEtg, alf, adf, auf);
    fps_kernel<<<B_, 512, 0, stream>>>(xyz, sel);
    knn_kernel<<<B_ * G_, 256, 0, stream>>>(xyz, sel, nn);
    std_acc_kernel<<<256, 256, 0, stream>>>(xyz, sel, nn, acc);
    std_fin_kernel<<<1, 1, 0, stream>>>(acc, stdp);
    group_kernel<<<B_ * G_, 256, 0, stream>>>(xyz, feat, wEtg, b_embed, g_embed, be_embed,
        sel, nn, wta, alf, adf, auf, g_lin1, be_lin1, down_b, gd, bd, up_b, gu, bu, stdp, out);
}